// Round 2
// baseline (2200.815 us; speedup 1.0000x reference)
//
#include <hip/hip_runtime.h>
#include <hip/hip_bf16.h>

// GraphReconstructionGCN: N=50000, E=800000, GCN 128 -> 128 -> 64.
// Round 2: runtime dtype detection (bf16 vs f32 floats, int32 vs int64 indices),
// aggregate-then-transform layer 1 (linearity), atomic scatter baseline.
static constexpr int FIN   = 128;
static constexpr int FHID  = 128;
static constexpr int FOUTC = 64;

__device__ __forceinline__ float bfbits2f(unsigned short u) {
  union { unsigned i; float f; } c; c.i = ((unsigned)u) << 16; return c.f;
}
__device__ __forceinline__ unsigned short f2bfbits(float f) {
  union { float fv; unsigned i; } c; c.fv = f;
  unsigned i = c.i;
  unsigned r = i + 0x7FFFu + ((i >> 16) & 1u);  // RNE
  if ((i & 0x7F800000u) == 0x7F800000u) r = i;  // inf/nan passthrough
  return (unsigned short)(r >> 16);
}
__device__ __forceinline__ int ld_idx(const void* ei, int is64, long long off) {
  return is64 ? (int)((const long long*)ei)[off] : ((const int*)ei)[off];
}
__device__ __forceinline__ float ld_f(const void* p, int isbf, long long i) {
  return isbf ? bfbits2f(((const unsigned short*)p)[i]) : ((const float*)p)[i];
}
__device__ __forceinline__ float4 ld_f4(const void* p, int isbf, long long i) {  // i % 4 == 0
  if (isbf) {
    ushort4 v = *(const ushort4*)((const unsigned short*)p + i);
    return make_float4(bfbits2f(v.x), bfbits2f(v.y), bfbits2f(v.z), bfbits2f(v.w));
  }
  return *(const float4*)((const float*)p + i);
}
__device__ __forceinline__ void atomAddF(float* p, float v) { unsafeAtomicAdd(p, v); }

// flags[0]: 1 = float tensors are bf16, 0 = f32. flags[1]: 1 = indices int64, 0 = int32.
__global__ void probe_kernel(const unsigned short* __restrict__ xb,
                             const unsigned* __restrict__ eiw, int* __restrict__ flags) {
  if (threadIdx.x != 0 || blockIdx.x != 0) return;
  int isbf = 1;
  for (int k = 0; k < 256; ++k) {
    unsigned e = (xb[2 * k] >> 7) & 0xFFu;  // bf16 exponent field
    if (e >= 0xC0u) { isbf = 0; break; }    // |v| >= 2^65 or NaN/inf: impossible for N(0,1) bf16
  }
  int is64 = 1;
  for (int k = 0; k < 64; ++k)
    if (eiw[2 * k + 1] != 0u) { is64 = 0; break; }  // int64 high words are 0 (idx < 50000)
  flags[0] = isbf;
  flags[1] = is64;
}

__global__ void init_deg(float* __restrict__ deg, int n) {
  int i = blockIdx.x * 256 + threadIdx.x;
  if (i < n) deg[i] = 1.0f;  // self-loop weight
}

__global__ void accum_deg(const void* __restrict__ ei, const void* __restrict__ ew,
                          const int* __restrict__ flg, float* __restrict__ deg, int E) {
  int e = blockIdx.x * 256 + threadIdx.x;
  if (e >= E) return;
  int d = ld_idx(ei, flg[1], (long long)E + e);
  atomAddF(&deg[d], ld_f(ew, flg[0], e));
}

__global__ void calc_dinv(const float* __restrict__ deg, float* __restrict__ dinv, int n) {
  int i = blockIdx.x * 256 + threadIdx.x;
  if (i < n) {
    float d = deg[i];
    dinv[i] = d > 0.f ? rsqrtf(d) : 0.f;
  }
}

__global__ void compute_norm(const void* __restrict__ ei, const void* __restrict__ ew,
                             const int* __restrict__ flg, const float* __restrict__ dinv,
                             float* __restrict__ normv, int E) {
  int e = blockIdx.x * 256 + threadIdx.x;
  if (e >= E) return;
  int is64 = flg[1];
  int s = ld_idx(ei, is64, e);
  int d = ld_idx(ei, is64, (long long)E + e);
  normv[e] = dinv[s] * ld_f(ew, flg[0], e) * dinv[d];
}

// agg[n, F] = dinv[n]^2 * X[n, F]   (self-loop term; doubles as accumulator init)
template <int F, bool DYNX>
__global__ void self_init(const void* __restrict__ X, const int* __restrict__ flg,
                          const float* __restrict__ dinv, float* __restrict__ agg, int n) {
  int idx = blockIdx.x * 256 + threadIdx.x;
  if (idx >= n * F) return;
  int nd = idx / F;
  float di = dinv[nd];
  float xv;
  if constexpr (DYNX) xv = ld_f(X, flg[0], idx);
  else xv = ((const float*)X)[idx];
  agg[idx] = di * di * xv;
}

// agg[dst, c*4:+4] += normv[e] * X[src, c*4:+4]; one thread per (edge, 4 features)
template <int F, bool DYNX>
__launch_bounds__(256)
__global__ void scatter_edges(const void* __restrict__ ei, const int* __restrict__ flg,
                              const float* __restrict__ normv, const void* __restrict__ X,
                              float* __restrict__ agg, int E) {
  constexpr int C = F / 4;
  int gid = blockIdx.x * 256 + threadIdx.x;
  if (gid >= E * C) return;
  int e = gid / C;
  int c = gid - e * C;
  int is64 = flg[1];
  int s = ld_idx(ei, is64, e);
  int d = ld_idx(ei, is64, (long long)E + e);
  float nrm = normv[e];
  float4 v;
  if constexpr (DYNX) v = ld_f4(X, flg[0], (long long)s * F + c * 4);
  else v = *(const float4*)((const float*)X + (long long)s * F + c * 4);
  float* o = agg + (long long)d * F + c * 4;
  atomAddF(o + 0, nrm * v.x);
  atomAddF(o + 1, nrm * v.y);
  atomAddF(o + 2, nrm * v.z);
  atomAddF(o + 3, nrm * v.w);
}

// C[n, FOUT] = act(A[n, K] @ W[K, FOUT] + b). A: f32 or internal bf16. W/b: dtype per flag.
// W staged in LDS in K-chunks of 64 (f32), A tile (ROWS x K f32) staged once. <=48KB LDS.
template <bool ABF16, int K, int FOUT, int ROWS, bool RELU, bool OUTBF16>
__launch_bounds__(256)
__global__ void gemm_kernel(const void* __restrict__ A, const void* __restrict__ W,
                            const void* __restrict__ bias, const int* __restrict__ flg,
                            void* __restrict__ C, int nrows) {
  constexpr int KC = 64;
  constexpr int CG = FOUT / 4;    // column groups of 4
  constexpr int RS = 256 / CG;    // row slots
  constexpr int RPT = ROWS / RS;  // rows per thread
  static_assert(ROWS % RS == 0 && K % KC == 0, "");
  __shared__ float Wl[KC * FOUT];
  __shared__ float Al[ROWS * K];
  const int tid = threadIdx.x;
  const int r0 = blockIdx.x * ROWS;
  const int wbf = flg[0];

  // stage A tile (f32 in LDS), zero-pad past nrows
  if constexpr (ABF16) {
    for (int c = tid; c < ROWS * K / 8; c += 256) {
      int i0 = c * 8;
      int gr = r0 + i0 / K;
      float4 lo = make_float4(0, 0, 0, 0), hi = lo;
      if (gr < nrows) {
        const unsigned short* src = (const unsigned short*)A + (long long)gr * K + (i0 & (K - 1));
        ushort4 a = ((const ushort4*)src)[0];
        ushort4 b = ((const ushort4*)src)[1];
        lo = make_float4(bfbits2f(a.x), bfbits2f(a.y), bfbits2f(a.z), bfbits2f(a.w));
        hi = make_float4(bfbits2f(b.x), bfbits2f(b.y), bfbits2f(b.z), bfbits2f(b.w));
      }
      *(float4*)&Al[i0] = lo;
      *(float4*)&Al[i0 + 4] = hi;
    }
  } else {
    for (int c = tid; c < ROWS * K / 4; c += 256) {
      int i0 = c * 4;
      int gr = r0 + i0 / K;
      float4 v = make_float4(0, 0, 0, 0);
      if (gr < nrows) v = *(const float4*)((const float*)A + (long long)gr * K + (i0 & (K - 1)));
      *(float4*)&Al[i0] = v;
    }
  }

  const int cg = tid % CG;
  const int rs = tid / CG;
  float acc[RPT][4];
#pragma unroll
  for (int rp = 0; rp < RPT; rp++)
#pragma unroll
    for (int c = 0; c < 4; c++) acc[rp][c] = 0.f;

  for (int kc = 0; kc < K; kc += KC) {
    __syncthreads();  // Wl reuse safety (and covers Al on first pass together with next sync)
    if (wbf) {
      for (int c = tid; c < KC * FOUT / 8; c += 256) {
        int i0 = c * 8;
        const unsigned short* src = (const unsigned short*)W + (long long)kc * FOUT + i0;
        ushort4 a = ((const ushort4*)src)[0];
        ushort4 b = ((const ushort4*)src)[1];
        *(float4*)&Wl[i0] = make_float4(bfbits2f(a.x), bfbits2f(a.y), bfbits2f(a.z), bfbits2f(a.w));
        *(float4*)&Wl[i0 + 4] =
            make_float4(bfbits2f(b.x), bfbits2f(b.y), bfbits2f(b.z), bfbits2f(b.w));
      }
    } else {
      for (int c = tid; c < KC * FOUT / 4; c += 256) {
        int i0 = c * 4;
        *(float4*)&Wl[i0] = *(const float4*)((const float*)W + (long long)kc * FOUT + i0);
      }
    }
    __syncthreads();
#pragma unroll 4
    for (int k2 = 0; k2 < KC; ++k2) {
      float4 wv = *(const float4*)&Wl[k2 * FOUT + cg * 4];
      int k = kc + k2;
#pragma unroll
      for (int rp = 0; rp < RPT; ++rp) {
        float av = Al[(rs + rp * RS) * K + k];
        acc[rp][0] = fmaf(av, wv.x, acc[rp][0]);
        acc[rp][1] = fmaf(av, wv.y, acc[rp][1]);
        acc[rp][2] = fmaf(av, wv.z, acc[rp][2]);
        acc[rp][3] = fmaf(av, wv.w, acc[rp][3]);
      }
    }
  }

  float bv0 = 0.f, bv1 = 0.f, bv2 = 0.f, bv3 = 0.f;
  if (bias) {
    bv0 = ld_f(bias, wbf, cg * 4 + 0);
    bv1 = ld_f(bias, wbf, cg * 4 + 1);
    bv2 = ld_f(bias, wbf, cg * 4 + 2);
    bv3 = ld_f(bias, wbf, cg * 4 + 3);
  }
#pragma unroll
  for (int rp = 0; rp < RPT; ++rp) {
    int gr = r0 + rs + rp * RS;
    if (gr >= nrows) continue;
    float o0 = acc[rp][0] + bv0, o1 = acc[rp][1] + bv1;
    float o2 = acc[rp][2] + bv2, o3 = acc[rp][3] + bv3;
    if (RELU) {
      o0 = fmaxf(o0, 0.f); o1 = fmaxf(o1, 0.f);
      o2 = fmaxf(o2, 0.f); o3 = fmaxf(o3, 0.f);
    }
    long long off = (long long)gr * FOUT + cg * 4;
    if constexpr (OUTBF16) {
      ushort4 pk = make_ushort4(f2bfbits(o0), f2bfbits(o1), f2bfbits(o2), f2bfbits(o3));
      *(ushort4*)((unsigned short*)C + off) = pk;
    } else {
      *(float4*)((float*)C + off) = make_float4(o0, o1, o2, o3);
    }
  }
}

// out = agg2 + b2, written per detected float dtype
__global__ void final_out(const float* __restrict__ agg2, const void* __restrict__ b2,
                          const int* __restrict__ flg, void* __restrict__ out, int n) {
  int idx = blockIdx.x * 256 + threadIdx.x;
  if (idx >= n * FOUTC) return;
  int f = idx & (FOUTC - 1);
  int isbf = flg[0];
  float v = agg2[idx] + ld_f(b2, isbf, f);
  if (isbf) ((unsigned short*)out)[idx] = f2bfbits(v);
  else ((float*)out)[idx] = v;
}

extern "C" void kernel_launch(void* const* d_in, const int* in_sizes, int n_in, void* d_out,
                              int out_size, void* d_ws, size_t ws_size, hipStream_t stream) {
  const void* x  = d_in[0];
  const void* ei = d_in[1];
  const void* ew = d_in[2];
  const void* W1 = d_in[3];
  const void* b1 = d_in[4];
  const void* W2 = d_in[5];
  const void* b2 = d_in[6];

  const int N = in_sizes[0] / FIN;  // 50000
  const int E = in_sizes[1] / 2;    // 800000

  // ws layout (f32 units): flags[16] | deg[N] | dinv[N] | normv[E] | R[N*128] | H1(bf16, N*128)
  // R: layer1 agg (N*128); layer2 reuses R as hw2[N*64] + agg2[N*64]. Total ~42 MB.
  float* ws = (float*)d_ws;
  int* flags = (int*)d_ws;
  float* deg = ws + 16;
  float* dinv = deg + N;
  float* normv = dinv + N;
  float* R = normv + E;
  float* hw2 = R;
  float* agg2 = R + (size_t)N * FOUTC;
  unsigned short* H1 = (unsigned short*)(R + (size_t)N * FHID);

  const int B = 256;
  probe_kernel<<<1, 64, 0, stream>>>((const unsigned short*)x, (const unsigned*)ei, flags);
  init_deg<<<(N + B - 1) / B, B, 0, stream>>>(deg, N);
  accum_deg<<<(E + B - 1) / B, B, 0, stream>>>(ei, ew, flags, deg, E);
  calc_dinv<<<(N + B - 1) / B, B, 0, stream>>>(deg, dinv, N);
  compute_norm<<<(E + B - 1) / B, B, 0, stream>>>(ei, ew, flags, dinv, normv, E);

  // layer 1 (aggregate-then-transform): agg1 = dinv^2*x + scatter(norm*x[src]);
  // H1 = relu(agg1 @ W1 + b1)  (bf16)
  self_init<FIN, true><<<((N * FIN) + B - 1) / B, B, 0, stream>>>(x, flags, dinv, R, N);
  scatter_edges<FIN, true>
      <<<((E * (FIN / 4)) + B - 1) / B, B, 0, stream>>>(ei, flags, normv, x, R, E);
  gemm_kernel<false, FIN, FHID, 32, true, true>
      <<<(N + 31) / 32, B, 0, stream>>>(R, W1, b1, flags, H1, N);

  // layer 2 (transform-then-aggregate): hw2 = H1 @ W2; agg2 = dinv^2*hw2 + scatter(norm*hw2[src]);
  // out = agg2 + b2
  gemm_kernel<true, FHID, FOUTC, 32, false, false>
      <<<(N + 31) / 32, B, 0, stream>>>(H1, W2, nullptr, flags, hw2, N);
  self_init<FOUTC, false><<<((N * FOUTC) + B - 1) / B, B, 0, stream>>>(hw2, flags, dinv, agg2, N);
  scatter_edges<FOUTC, false>
      <<<((E * (FOUTC / 4)) + B - 1) / B, B, 0, stream>>>(ei, flags, normv, hw2, agg2, E);
  final_out<<<((N * FOUTC) + B - 1) / B, B, 0, stream>>>(agg2, b2, flags, d_out, N);
}

// Round 3
// 359.665 us; speedup vs baseline: 6.1191x; 6.1191x over previous
//
#include <hip/hip_runtime.h>
#include <hip/hip_bf16.h>

// GraphReconstructionGCN: N=50000, E=800000, GCN 128 -> 128 -> 64.
// Round 3: CSR build (count/scan/fill) + wave-per-node register gather replaces
// the atomic scatter (was 2x ~1.3ms, WRITE_SIZE 1.6GB of atomic RMW traffic).
static constexpr int FIN   = 128;
static constexpr int FHID  = 128;
static constexpr int FOUTC = 64;

__device__ __forceinline__ float bfbits2f(unsigned short u) {
  union { unsigned i; float f; } c; c.i = ((unsigned)u) << 16; return c.f;
}
__device__ __forceinline__ void unpack_bf2(unsigned u, float& lo, float& hi) {
  union { unsigned i; float f; } a, b;
  a.i = u << 16;
  b.i = u & 0xffff0000u;
  lo = a.f; hi = b.f;
}
__device__ __forceinline__ unsigned short f2bfbits(float f) {
  union { float fv; unsigned i; } c; c.fv = f;
  unsigned i = c.i;
  unsigned r = i + 0x7FFFu + ((i >> 16) & 1u);  // RNE
  if ((i & 0x7F800000u) == 0x7F800000u) r = i;  // inf/nan passthrough
  return (unsigned short)(r >> 16);
}
__device__ __forceinline__ int ld_idx(const void* ei, int is64, long long off) {
  return is64 ? (int)((const long long*)ei)[off] : ((const int*)ei)[off];
}
__device__ __forceinline__ float ld_f(const void* p, int isbf, long long i) {
  return isbf ? bfbits2f(((const unsigned short*)p)[i]) : ((const float*)p)[i];
}

// flags[0]: 1 = float tensors are bf16, 0 = f32. flags[1]: 1 = indices int64, 0 = int32.
__global__ void probe_kernel(const unsigned short* __restrict__ xb,
                             const unsigned* __restrict__ eiw, int* __restrict__ flags) {
  if (threadIdx.x != 0 || blockIdx.x != 0) return;
  int isbf = 1;
  for (int k = 0; k < 256; ++k) {
    unsigned e = (xb[2 * k] >> 7) & 0xFFu;  // bf16 exponent field
    if (e >= 0xC0u) { isbf = 0; break; }    // impossible for N(0,1)-scale bf16
  }
  int is64 = 1;
  for (int k = 0; k < 64; ++k)
    if (eiw[2 * k + 1] != 0u) { is64 = 0; break; }  // int64 high words are 0 (idx < 50000)
  flags[0] = isbf;
  flags[1] = is64;
}

__global__ void init_cnt(int* __restrict__ cnt, int n) {
  int i = blockIdx.x * 256 + threadIdx.x;
  if (i < n) cnt[i] = 0;
}

__global__ void count_edges(const void* __restrict__ ei, const int* __restrict__ flg,
                            int* __restrict__ cnt, int E) {
  int e = blockIdx.x * 256 + threadIdx.x;
  if (e >= E) return;
  int d = ld_idx(ei, flg[1], (long long)E + e);
  atomicAdd(&cnt[d], 1);
}

// 2-level exclusive scan of cnt[N] -> rowex (within-block exclusive) + bsums
__global__ void scanA(const int* __restrict__ cnt, int* __restrict__ rowex,
                      int* __restrict__ bsums, int n) {
  __shared__ int s[256];
  int tid = threadIdx.x;
  int i = blockIdx.x * 256 + tid;
  int v = (i < n) ? cnt[i] : 0;
  s[tid] = v;
  __syncthreads();
  for (int off = 1; off < 256; off <<= 1) {
    int t = (tid >= off) ? s[tid - off] : 0;
    __syncthreads();
    s[tid] += t;
    __syncthreads();
  }
  if (i < n) rowex[i] = s[tid] - v;  // exclusive within block
  if (tid == 255) bsums[blockIdx.x] = s[255];
}

__global__ void scanB(int* __restrict__ bsums, int nb) {
  __shared__ int s[256];
  int tid = threadIdx.x;
  int v = (tid < nb) ? bsums[tid] : 0;
  s[tid] = v;
  __syncthreads();
  for (int off = 1; off < 256; off <<= 1) {
    int t = (tid >= off) ? s[tid - off] : 0;
    __syncthreads();
    s[tid] += t;
    __syncthreads();
  }
  if (tid < nb) bsums[tid] = s[tid] - v;  // exclusive
}

// rowptr[i] = rowex[i] + bsums[blk] (in-place over rowex); fill[i] = rowptr[i]
__global__ void scanC(int* __restrict__ rowptr, const int* __restrict__ bsums,
                      int* __restrict__ fill, int n) {
  int i = blockIdx.x * 256 + threadIdx.x;
  if (i >= n) return;
  int v = rowptr[i] + bsums[blockIdx.x];
  rowptr[i] = v;
  fill[i] = v;
}

__global__ void fill_edges(const void* __restrict__ ei, const void* __restrict__ ew,
                           const int* __restrict__ flg, int* __restrict__ fill,
                           int* __restrict__ csr_src, float* __restrict__ csr_w, int E) {
  int e = blockIdx.x * 256 + threadIdx.x;
  if (e >= E) return;
  int is64 = flg[1];
  int s = ld_idx(ei, is64, e);
  int d = ld_idx(ei, is64, (long long)E + e);
  int p = atomicAdd(&fill[d], 1);
  csr_src[p] = s;
  csr_w[p] = ld_f(ew, flg[0], e);
}

// dinv[n] = rsqrt(1 + sum of incoming weights)
__global__ void node_dinv(const int* __restrict__ rowptr, const int* __restrict__ cnt,
                          const float* __restrict__ csr_w, float* __restrict__ dinv, int n) {
  int i = blockIdx.x * 256 + threadIdx.x;
  if (i >= n) return;
  int st = rowptr[i], c = cnt[i];
  float s = 1.0f;  // self-loop weight
  for (int j = 0; j < c; ++j) s += csr_w[st + j];
  dinv[i] = rsqrtf(s);
}

// csr_w[j] = dinv[src] * w * dinv[dst]
__global__ void norm_rewrite(const int* __restrict__ rowptr, const int* __restrict__ cnt,
                             const int* __restrict__ csr_src, const float* __restrict__ dinv,
                             float* __restrict__ csr_w, int n) {
  int i = blockIdx.x * 256 + threadIdx.x;
  if (i >= n) return;
  int st = rowptr[i], c = cnt[i];
  float di = dinv[i];
  for (int j = 0; j < c; ++j) csr_w[st + j] = dinv[csr_src[st + j]] * csr_w[st + j] * di;
}

// agg1[n, 0:128] = dinv[n]^2 * x[n] + sum_e norm_e * x[src_e]; one wave per node.
__launch_bounds__(256)
__global__ void gather_l1(const void* __restrict__ x, const int* __restrict__ flg,
                          const int* __restrict__ rowptr, const int* __restrict__ cnt,
                          const int* __restrict__ csr_src, const float* __restrict__ csr_w,
                          const float* __restrict__ dinv, float* __restrict__ agg, int n) {
  int wid = (blockIdx.x * 256 + threadIdx.x) >> 6;
  int lane = threadIdx.x & 63;
  if (wid >= n) return;
  int st = rowptr[wid], c = cnt[wid];
  float a0 = 0.f, a1 = 0.f;
  float di = dinv[wid];
  if (flg[0]) {
    const unsigned* xb = (const unsigned*)x;  // 2 bf16 per word, 64 words per row
    int j = 0;
    for (; j + 2 <= c; j += 2) {
      int s0 = csr_src[st + j], s1 = csr_src[st + j + 1];
      float w0 = csr_w[st + j], w1 = csr_w[st + j + 1];
      unsigned u0 = xb[(long long)s0 * 64 + lane];
      unsigned u1 = xb[(long long)s1 * 64 + lane];
      float l0, h0, l1, h1;
      unpack_bf2(u0, l0, h0);
      unpack_bf2(u1, l1, h1);
      a0 = fmaf(w0, l0, a0); a1 = fmaf(w0, h0, a1);
      a0 = fmaf(w1, l1, a0); a1 = fmaf(w1, h1, a1);
    }
    if (j < c) {
      int s0 = csr_src[st + j];
      float w0 = csr_w[st + j];
      float l0, h0;
      unpack_bf2(xb[(long long)s0 * 64 + lane], l0, h0);
      a0 = fmaf(w0, l0, a0); a1 = fmaf(w0, h0, a1);
    }
    float l0, h0;
    unpack_bf2(xb[(long long)wid * 64 + lane], l0, h0);
    a0 = fmaf(di * di, l0, a0); a1 = fmaf(di * di, h0, a1);
  } else {
    const float2* xf = (const float2*)x;  // 64 float2 per row
    int j = 0;
    for (; j + 2 <= c; j += 2) {
      int s0 = csr_src[st + j], s1 = csr_src[st + j + 1];
      float w0 = csr_w[st + j], w1 = csr_w[st + j + 1];
      float2 v0 = xf[(long long)s0 * 64 + lane];
      float2 v1 = xf[(long long)s1 * 64 + lane];
      a0 = fmaf(w0, v0.x, a0); a1 = fmaf(w0, v0.y, a1);
      a0 = fmaf(w1, v1.x, a0); a1 = fmaf(w1, v1.y, a1);
    }
    if (j < c) {
      int s0 = csr_src[st + j];
      float w0 = csr_w[st + j];
      float2 v0 = xf[(long long)s0 * 64 + lane];
      a0 = fmaf(w0, v0.x, a0); a1 = fmaf(w0, v0.y, a1);
    }
    float2 v = xf[(long long)wid * 64 + lane];
    a0 = fmaf(di * di, v.x, a0); a1 = fmaf(di * di, v.y, a1);
  }
  ((float2*)agg)[(long long)wid * 64 + lane] = make_float2(a0, a1);
}

// out[n, 0:64] = dinv^2*hw2[n] + sum_e norm_e*hw2[src] + b2; one wave per node.
__launch_bounds__(256)
__global__ void gather_l2(const float* __restrict__ hw2, const int* __restrict__ flg,
                          const int* __restrict__ rowptr, const int* __restrict__ cnt,
                          const int* __restrict__ csr_src, const float* __restrict__ csr_w,
                          const float* __restrict__ dinv, const void* __restrict__ b2,
                          void* __restrict__ out, int n) {
  int wid = (blockIdx.x * 256 + threadIdx.x) >> 6;
  int lane = threadIdx.x & 63;
  if (wid >= n) return;
  int st = rowptr[wid], c = cnt[wid];
  float a = 0.f;
  int j = 0;
  for (; j + 2 <= c; j += 2) {
    int s0 = csr_src[st + j], s1 = csr_src[st + j + 1];
    float w0 = csr_w[st + j], w1 = csr_w[st + j + 1];
    float v0 = hw2[(long long)s0 * 64 + lane];
    float v1 = hw2[(long long)s1 * 64 + lane];
    a = fmaf(w0, v0, a);
    a = fmaf(w1, v1, a);
  }
  if (j < c) {
    a = fmaf(csr_w[st + j], hw2[(long long)csr_src[st + j] * 64 + lane], a);
  }
  float di = dinv[wid];
  a = fmaf(di * di, hw2[(long long)wid * 64 + lane], a);
  int isbf = flg[0];
  a += ld_f(b2, isbf, lane);
  if (isbf) ((unsigned short*)out)[(long long)wid * 64 + lane] = f2bfbits(a);
  else ((float*)out)[(long long)wid * 64 + lane] = a;
}

// C[n, FOUT] = act(A[n, K] @ W[K, FOUT] + b). A: f32 or internal bf16. W/b dtype per flag.
template <bool ABF16, int K, int FOUT, int ROWS, bool RELU, bool OUTBF16>
__launch_bounds__(256)
__global__ void gemm_kernel(const void* __restrict__ A, const void* __restrict__ W,
                            const void* __restrict__ bias, const int* __restrict__ flg,
                            void* __restrict__ C, int nrows) {
  constexpr int KC = 64;
  constexpr int CG = FOUT / 4;
  constexpr int RS = 256 / CG;
  constexpr int RPT = ROWS / RS;
  static_assert(ROWS % RS == 0 && K % KC == 0, "");
  __shared__ float Wl[KC * FOUT];
  __shared__ float Al[ROWS * K];
  const int tid = threadIdx.x;
  const int r0 = blockIdx.x * ROWS;
  const int wbf = flg[0];

  if constexpr (ABF16) {
    for (int c = tid; c < ROWS * K / 8; c += 256) {
      int i0 = c * 8;
      int gr = r0 + i0 / K;
      float4 lo = make_float4(0, 0, 0, 0), hi = lo;
      if (gr < nrows) {
        const unsigned short* src = (const unsigned short*)A + (long long)gr * K + (i0 & (K - 1));
        ushort4 a = ((const ushort4*)src)[0];
        ushort4 b = ((const ushort4*)src)[1];
        lo = make_float4(bfbits2f(a.x), bfbits2f(a.y), bfbits2f(a.z), bfbits2f(a.w));
        hi = make_float4(bfbits2f(b.x), bfbits2f(b.y), bfbits2f(b.z), bfbits2f(b.w));
      }
      *(float4*)&Al[i0] = lo;
      *(float4*)&Al[i0 + 4] = hi;
    }
  } else {
    for (int c = tid; c < ROWS * K / 4; c += 256) {
      int i0 = c * 4;
      int gr = r0 + i0 / K;
      float4 v = make_float4(0, 0, 0, 0);
      if (gr < nrows) v = *(const float4*)((const float*)A + (long long)gr * K + (i0 & (K - 1)));
      *(float4*)&Al[i0] = v;
    }
  }

  const int cg = tid % CG;
  const int rs = tid / CG;
  float acc[RPT][4];
#pragma unroll
  for (int rp = 0; rp < RPT; rp++)
#pragma unroll
    for (int c = 0; c < 4; c++) acc[rp][c] = 0.f;

  for (int kc = 0; kc < K; kc += KC) {
    __syncthreads();
    if (wbf) {
      for (int c = tid; c < KC * FOUT / 8; c += 256) {
        int i0 = c * 8;
        const unsigned short* src = (const unsigned short*)W + (long long)kc * FOUT + i0;
        ushort4 a = ((const ushort4*)src)[0];
        ushort4 b = ((const ushort4*)src)[1];
        *(float4*)&Wl[i0] = make_float4(bfbits2f(a.x), bfbits2f(a.y), bfbits2f(a.z), bfbits2f(a.w));
        *(float4*)&Wl[i0 + 4] =
            make_float4(bfbits2f(b.x), bfbits2f(b.y), bfbits2f(b.z), bfbits2f(b.w));
      }
    } else {
      for (int c = tid; c < KC * FOUT / 4; c += 256) {
        int i0 = c * 4;
        *(float4*)&Wl[i0] = *(const float4*)((const float*)W + (long long)kc * FOUT + i0);
      }
    }
    __syncthreads();
#pragma unroll 4
    for (int k2 = 0; k2 < KC; ++k2) {
      float4 wv = *(const float4*)&Wl[k2 * FOUT + cg * 4];
      int k = kc + k2;
#pragma unroll
      for (int rp = 0; rp < RPT; ++rp) {
        float av = Al[(rs + rp * RS) * K + k];
        acc[rp][0] = fmaf(av, wv.x, acc[rp][0]);
        acc[rp][1] = fmaf(av, wv.y, acc[rp][1]);
        acc[rp][2] = fmaf(av, wv.z, acc[rp][2]);
        acc[rp][3] = fmaf(av, wv.w, acc[rp][3]);
      }
    }
  }

  float bv0 = 0.f, bv1 = 0.f, bv2 = 0.f, bv3 = 0.f;
  if (bias) {
    bv0 = ld_f(bias, wbf, cg * 4 + 0);
    bv1 = ld_f(bias, wbf, cg * 4 + 1);
    bv2 = ld_f(bias, wbf, cg * 4 + 2);
    bv3 = ld_f(bias, wbf, cg * 4 + 3);
  }
#pragma unroll
  for (int rp = 0; rp < RPT; ++rp) {
    int gr = r0 + rs + rp * RPT == 0 ? r0 + rs + rp * RS : r0 + rs + rp * RS;  // r0 + rs + rp*RS
    gr = r0 + rs + rp * RS;
    if (gr >= nrows) continue;
    float o0 = acc[rp][0] + bv0, o1 = acc[rp][1] + bv1;
    float o2 = acc[rp][2] + bv2, o3 = acc[rp][3] + bv3;
    if (RELU) {
      o0 = fmaxf(o0, 0.f); o1 = fmaxf(o1, 0.f);
      o2 = fmaxf(o2, 0.f); o3 = fmaxf(o3, 0.f);
    }
    long long off = (long long)gr * FOUT + cg * 4;
    if constexpr (OUTBF16) {
      ushort4 pk = make_ushort4(f2bfbits(o0), f2bfbits(o1), f2bfbits(o2), f2bfbits(o3));
      *(ushort4*)((unsigned short*)C + off) = pk;
    } else {
      *(float4*)((float*)C + off) = make_float4(o0, o1, o2, o3);
    }
  }
}

extern "C" void kernel_launch(void* const* d_in, const int* in_sizes, int n_in, void* d_out,
                              int out_size, void* d_ws, size_t ws_size, hipStream_t stream) {
  const void* x  = d_in[0];
  const void* ei = d_in[1];
  const void* ew = d_in[2];
  const void* W1 = d_in[3];
  const void* b1 = d_in[4];
  const void* W2 = d_in[5];
  const void* b2 = d_in[6];

  const int N = in_sizes[0] / FIN;  // 50000
  const int E = in_sizes[1] / 2;    // 800000
  const int B = 256;
  const int NB = (N + B - 1) / B;   // scan blocks (196)

  // ws layout: flags[16] | cnt[N] | rowptr[N] | bsums[256] | fill[N] | dinv[N] |
  //            csr_src[E] | csr_w[E] | R[N*128 f32] (agg1; hw2 aliases) | H1[N*128 bf16]
  int* flags  = (int*)d_ws;
  int* cnt    = flags + 16;
  int* rowptr = cnt + N;
  int* bsums  = rowptr + N;
  int* fill   = bsums + 256;
  float* dinv = (float*)(fill + N);
  int* csr_src = (int*)(dinv + N);
  float* csr_w = (float*)(csr_src + E);
  float* R     = csr_w + E;
  unsigned short* H1 = (unsigned short*)(R + (size_t)N * FHID);
  float* hw2 = R;  // agg1 dead after gemm1

  probe_kernel<<<1, 64, 0, stream>>>((const unsigned short*)x, (const unsigned*)ei, flags);

  // CSR build (by dst)
  init_cnt<<<NB, B, 0, stream>>>(cnt, N);
  count_edges<<<(E + B - 1) / B, B, 0, stream>>>(ei, flags, cnt, E);
  scanA<<<NB, B, 0, stream>>>(cnt, rowptr, bsums, N);
  scanB<<<1, B, 0, stream>>>(bsums, NB);
  scanC<<<NB, B, 0, stream>>>(rowptr, bsums, fill, N);
  fill_edges<<<(E + B - 1) / B, B, 0, stream>>>(ei, ew, flags, fill, csr_src, csr_w, E);
  node_dinv<<<NB, B, 0, stream>>>(rowptr, cnt, csr_w, dinv, N);
  norm_rewrite<<<NB, B, 0, stream>>>(rowptr, cnt, csr_src, dinv, csr_w, N);

  // layer 1 (aggregate-then-transform): agg1 = gather(x); H1 = relu(agg1 @ W1 + b1)
  gather_l1<<<(N + 3) / 4, B, 0, stream>>>(x, flags, rowptr, cnt, csr_src, csr_w, dinv, R, N);
  gemm_kernel<false, FIN, FHID, 32, true, true>
      <<<(N + 31) / 32, B, 0, stream>>>(R, W1, b1, flags, H1, N);

  // layer 2 (transform-then-aggregate): hw2 = H1 @ W2; out = gather(hw2) + b2
  gemm_kernel<true, FHID, FOUTC, 32, false, false>
      <<<(N + 31) / 32, B, 0, stream>>>(H1, W2, nullptr, flags, hw2, N);
  gather_l2<<<(N + 3) / 4, B, 0, stream>>>(hw2, flags, rowptr, cnt, csr_src, csr_w, dinv, b2,
                                           d_out, N);
}

// Round 4
// 333.062 us; speedup vs baseline: 6.6078x; 1.0799x over previous
//
#include <hip/hip_runtime.h>
#include <hip/hip_bf16.h>

// GraphReconstructionGCN: N=50000, E=800000, GCN 128 -> 128 -> 64.
// Round 4: MFMA bf16 GEMMs (16x16x32, XOR-swizzled LDS tiles), unroll-4 gathers,
// bf16 intermediates (agg1/H1/hw2), CSR build simplified (dinv folded into csr_w).
static constexpr int FIN   = 128;
static constexpr int FHID  = 128;
static constexpr int FOUTC = 64;

typedef short bf16x8 __attribute__((ext_vector_type(8)));
typedef float f32x4 __attribute__((ext_vector_type(4)));

__device__ __forceinline__ float bfbits2f(unsigned short u) {
  union { unsigned i; float f; } c; c.i = ((unsigned)u) << 16; return c.f;
}
__device__ __forceinline__ void unpack_bf2(unsigned u, float& lo, float& hi) {
  union { unsigned i; float f; } a, b;
  a.i = u << 16;
  b.i = u & 0xffff0000u;
  lo = a.f; hi = b.f;
}
__device__ __forceinline__ unsigned short f2bfbits(float f) {
  union { float fv; unsigned i; } c; c.fv = f;
  unsigned i = c.i;
  unsigned r = i + 0x7FFFu + ((i >> 16) & 1u);  // RNE
  if ((i & 0x7F800000u) == 0x7F800000u) r = i;  // inf/nan passthrough
  return (unsigned short)(r >> 16);
}
__device__ __forceinline__ int ld_idx(const void* ei, int is64, long long off) {
  return is64 ? (int)((const long long*)ei)[off] : ((const int*)ei)[off];
}
__device__ __forceinline__ float ld_f(const void* p, int isbf, long long i) {
  return isbf ? bfbits2f(((const unsigned short*)p)[i]) : ((const float*)p)[i];
}

// flags[0]: 1 = float tensors are bf16, 0 = f32. flags[1]: 1 = indices int64, 0 = int32.
__global__ void probe_kernel(const unsigned short* __restrict__ xb,
                             const unsigned* __restrict__ eiw, int* __restrict__ flags) {
  if (threadIdx.x != 0 || blockIdx.x != 0) return;
  int isbf = 1;
  for (int k = 0; k < 256; ++k) {
    unsigned e = (xb[2 * k] >> 7) & 0xFFu;
    if (e >= 0xC0u) { isbf = 0; break; }
  }
  int is64 = 1;
  for (int k = 0; k < 64; ++k)
    if (eiw[2 * k + 1] != 0u) { is64 = 0; break; }
  flags[0] = isbf;
  flags[1] = is64;
}

__global__ void init_nd(int* __restrict__ cnt, float* __restrict__ deg, int n) {
  int i = blockIdx.x * 256 + threadIdx.x;
  if (i < n) { cnt[i] = 0; deg[i] = 1.0f; }  // deg starts at self-loop weight
}

__global__ void count_edges(const void* __restrict__ ei, const void* __restrict__ ew,
                            const int* __restrict__ flg, int* __restrict__ cnt,
                            float* __restrict__ deg, int E) {
  int e = blockIdx.x * 256 + threadIdx.x;
  if (e >= E) return;
  int d = ld_idx(ei, flg[1], (long long)E + e);
  atomicAdd(&cnt[d], 1);
  unsafeAtomicAdd(&deg[d], ld_f(ew, flg[0], e));
}

__global__ void calc_dinv(float* __restrict__ degdinv, int n) {
  int i = blockIdx.x * 256 + threadIdx.x;
  if (i < n) degdinv[i] = rsqrtf(degdinv[i]);  // deg >= 1 always
}

// 2-level exclusive scan of cnt[N]
__global__ void scanA(const int* __restrict__ cnt, int* __restrict__ rowex,
                      int* __restrict__ bsums, int n) {
  __shared__ int s[256];
  int tid = threadIdx.x;
  int i = blockIdx.x * 256 + tid;
  int v = (i < n) ? cnt[i] : 0;
  s[tid] = v;
  __syncthreads();
  for (int off = 1; off < 256; off <<= 1) {
    int t = (tid >= off) ? s[tid - off] : 0;
    __syncthreads();
    s[tid] += t;
    __syncthreads();
  }
  if (i < n) rowex[i] = s[tid] - v;
  if (tid == 255) bsums[blockIdx.x] = s[255];
}

__global__ void scanB(int* __restrict__ bsums, int nb) {
  __shared__ int s[256];
  int tid = threadIdx.x;
  int v = (tid < nb) ? bsums[tid] : 0;
  s[tid] = v;
  __syncthreads();
  for (int off = 1; off < 256; off <<= 1) {
    int t = (tid >= off) ? s[tid - off] : 0;
    __syncthreads();
    s[tid] += t;
    __syncthreads();
  }
  if (tid < nb) bsums[tid] = s[tid] - v;
}

__global__ void scanC(int* __restrict__ rowptr, const int* __restrict__ bsums,
                      int* __restrict__ fill, int n) {
  int i = blockIdx.x * 256 + threadIdx.x;
  if (i >= n) return;
  int v = rowptr[i] + bsums[blockIdx.x];
  rowptr[i] = v;
  fill[i] = v;
}

// csr_w[p] = dinv[src] * w   (dinv[dst] applied wave-uniformly in the gathers)
__global__ void fill_edges(const void* __restrict__ ei, const void* __restrict__ ew,
                           const int* __restrict__ flg, const float* __restrict__ dinv,
                           int* __restrict__ fill, int* __restrict__ csr_src,
                           float* __restrict__ csr_w, int E) {
  int e = blockIdx.x * 256 + threadIdx.x;
  if (e >= E) return;
  int is64 = flg[1];
  int s = ld_idx(ei, is64, e);
  int d = ld_idx(ei, is64, (long long)E + e);
  int p = atomicAdd(&fill[d], 1);
  csr_src[p] = s;
  csr_w[p] = dinv[s] * ld_f(ew, flg[0], e);
}

// Wt1[n*128+k] = W1[k][n]; Wt2[n*128+k] = W2[k][n]  (bf16, dtype-converted)
__global__ void transpose_w(const void* __restrict__ W1, const void* __restrict__ W2,
                            const int* __restrict__ flg, unsigned short* __restrict__ Wt1,
                            unsigned short* __restrict__ Wt2) {
  int i = blockIdx.x * 256 + threadIdx.x;
  int f = flg[0];
  if (i < 128 * 128) {
    int k = i >> 7, n = i & 127;
    Wt1[n * 128 + k] = f2bfbits(ld_f(W1, f, i));
  } else {
    int j = i - 128 * 128;  // j < 128*64
    int k = j >> 6, n = j & 63;
    Wt2[n * 128 + k] = f2bfbits(ld_f(W2, f, j));
  }
}

// agg1[n,:] = dinv[n] * sum_e csr_w[e]*x[src_e] + dinv[n]^2 * x[n]; bf16 out.
// One wave per node, lane covers 2 features (128-wide). Unroll 4 for MLP.
__launch_bounds__(256)
__global__ void gather_l1(const void* __restrict__ x, const int* __restrict__ flg,
                          const int* __restrict__ rowptr, const int* __restrict__ cnt,
                          const int* __restrict__ csr_src, const float* __restrict__ csr_w,
                          const float* __restrict__ dinv, unsigned* __restrict__ agg, int n) {
  int wid = (blockIdx.x * 256 + threadIdx.x) >> 6;
  int lane = threadIdx.x & 63;
  if (wid >= n) return;
  int st = rowptr[wid], e = st + cnt[wid];
  float a0 = 0.f, a1 = 0.f;
  float di = dinv[wid];
  float l, h;
  if (flg[0]) {
    const unsigned* xb = (const unsigned*)x;  // 2 bf16/word, 64 words/row
    int j = st;
    for (; j + 4 <= e; j += 4) {
      int s0 = csr_src[j], s1 = csr_src[j + 1], s2 = csr_src[j + 2], s3 = csr_src[j + 3];
      float w0 = csr_w[j], w1 = csr_w[j + 1], w2 = csr_w[j + 2], w3 = csr_w[j + 3];
      unsigned u0 = xb[(size_t)s0 * 64 + lane];
      unsigned u1 = xb[(size_t)s1 * 64 + lane];
      unsigned u2 = xb[(size_t)s2 * 64 + lane];
      unsigned u3 = xb[(size_t)s3 * 64 + lane];
      unpack_bf2(u0, l, h); a0 = fmaf(w0, l, a0); a1 = fmaf(w0, h, a1);
      unpack_bf2(u1, l, h); a0 = fmaf(w1, l, a0); a1 = fmaf(w1, h, a1);
      unpack_bf2(u2, l, h); a0 = fmaf(w2, l, a0); a1 = fmaf(w2, h, a1);
      unpack_bf2(u3, l, h); a0 = fmaf(w3, l, a0); a1 = fmaf(w3, h, a1);
    }
    for (; j < e; ++j) {
      float w0 = csr_w[j];
      unpack_bf2(xb[(size_t)csr_src[j] * 64 + lane], l, h);
      a0 = fmaf(w0, l, a0); a1 = fmaf(w0, h, a1);
    }
    unpack_bf2(xb[(size_t)wid * 64 + lane], l, h);
  } else {
    const float2* xf = (const float2*)x;
    int j = st;
    for (; j + 4 <= e; j += 4) {
      int s0 = csr_src[j], s1 = csr_src[j + 1], s2 = csr_src[j + 2], s3 = csr_src[j + 3];
      float w0 = csr_w[j], w1 = csr_w[j + 1], w2 = csr_w[j + 2], w3 = csr_w[j + 3];
      float2 v0 = xf[(size_t)s0 * 64 + lane];
      float2 v1 = xf[(size_t)s1 * 64 + lane];
      float2 v2 = xf[(size_t)s2 * 64 + lane];
      float2 v3 = xf[(size_t)s3 * 64 + lane];
      a0 = fmaf(w0, v0.x, a0); a1 = fmaf(w0, v0.y, a1);
      a0 = fmaf(w1, v1.x, a0); a1 = fmaf(w1, v1.y, a1);
      a0 = fmaf(w2, v2.x, a0); a1 = fmaf(w2, v2.y, a1);
      a0 = fmaf(w3, v3.x, a0); a1 = fmaf(w3, v3.y, a1);
    }
    for (; j < e; ++j) {
      float w0 = csr_w[j];
      float2 v0 = xf[(size_t)csr_src[j] * 64 + lane];
      a0 = fmaf(w0, v0.x, a0); a1 = fmaf(w0, v0.y, a1);
    }
    float2 v = xf[(size_t)wid * 64 + lane];
    l = v.x; h = v.y;
  }
  a0 = di * a0 + di * di * l;
  a1 = di * a1 + di * di * h;
  agg[(size_t)wid * 64 + lane] =
      (unsigned)f2bfbits(a0) | ((unsigned)f2bfbits(a1) << 16);
}

// out[n,:] = dinv[n]*sum_e csr_w[e]*hw2[src_e] + dinv[n]^2*hw2[n] + b2; hw2 bf16 64-wide.
__launch_bounds__(256)
__global__ void gather_l2(const unsigned short* __restrict__ hw2, const int* __restrict__ flg,
                          const int* __restrict__ rowptr, const int* __restrict__ cnt,
                          const int* __restrict__ csr_src, const float* __restrict__ csr_w,
                          const float* __restrict__ dinv, const void* __restrict__ b2,
                          void* __restrict__ out, int n) {
  int wid = (blockIdx.x * 256 + threadIdx.x) >> 6;
  int lane = threadIdx.x & 63;
  if (wid >= n) return;
  int st = rowptr[wid], e = st + cnt[wid];
  float a = 0.f;
  int j = st;
  for (; j + 4 <= e; j += 4) {
    int s0 = csr_src[j], s1 = csr_src[j + 1], s2 = csr_src[j + 2], s3 = csr_src[j + 3];
    float w0 = csr_w[j], w1 = csr_w[j + 1], w2 = csr_w[j + 2], w3 = csr_w[j + 3];
    float v0 = bfbits2f(hw2[(size_t)s0 * 64 + lane]);
    float v1 = bfbits2f(hw2[(size_t)s1 * 64 + lane]);
    float v2 = bfbits2f(hw2[(size_t)s2 * 64 + lane]);
    float v3 = bfbits2f(hw2[(size_t)s3 * 64 + lane]);
    a = fmaf(w0, v0, a); a = fmaf(w1, v1, a);
    a = fmaf(w2, v2, a); a = fmaf(w3, v3, a);
  }
  for (; j < e; ++j)
    a = fmaf(csr_w[j], bfbits2f(hw2[(size_t)csr_src[j] * 64 + lane]), a);
  float di = dinv[wid];
  a = di * a + di * di * bfbits2f(hw2[(size_t)wid * 64 + lane]);
  int isbf = flg[0];
  a += ld_f(b2, isbf, lane);
  if (isbf) ((unsigned short*)out)[(size_t)wid * 64 + lane] = f2bfbits(a);
  else ((float*)out)[(size_t)wid * 64 + lane] = a;
}

// C[M,FOUT](bf16) = act(A[M,128](bf16) @ W + b), W given as Wt[n][k] bf16.
// 128 rows/block, 4 waves; wave covers 32 rows x FOUT cols via 16x16x32 MFMA.
// LDS tiles use XOR-chunk swizzle (chunk = 8 bf16 = 16B) for uniform bank coverage.
// A-operand layout: m=lane&15, k=quad*8+j (m120); C/D: col=lane&15, row=quad*4+reg (m89).
template <int FOUT, bool RELU>
__launch_bounds__(256)
__global__ void gemm_mfma(const unsigned short* __restrict__ A,
                          const unsigned short* __restrict__ Wt,
                          const void* __restrict__ bias, const int* __restrict__ flg,
                          unsigned short* __restrict__ C, int M) {
  constexpr int NT = FOUT / 16;
  __shared__ unsigned short As[128 * 128];
  __shared__ unsigned short Ws[FOUT * 128];
  const int tid = threadIdx.x;
  const int r0 = blockIdx.x * 128;

  for (int i = tid; i < 128 * 16; i += 256) {  // A tile: 128 rows x 16 chunks
    int r = i >> 4, c = i & 15;
    uint4 v = make_uint4(0u, 0u, 0u, 0u);
    if (r0 + r < M) v = *(const uint4*)(A + (size_t)(r0 + r) * 128 + c * 8);
    *(uint4*)&As[r * 128 + ((c ^ (r & 15)) << 3)] = v;
  }
  for (int i = tid; i < FOUT * 16; i += 256) {  // Wt tile: FOUT rows x 16 chunks
    int r = i >> 4, c = i & 15;
    uint4 v = *(const uint4*)(Wt + (size_t)r * 128 + c * 8);
    *(uint4*)&Ws[r * 128 + ((c ^ (r & 15)) << 3)] = v;
  }
  __syncthreads();

  const int lane = tid & 63;
  const int wv = tid >> 6;
  const int ln15 = lane & 15;
  const int kq = lane >> 4;  // quad 0..3
  f32x4 acc[2][NT];
#pragma unroll
  for (int mi = 0; mi < 2; ++mi)
#pragma unroll
    for (int nt = 0; nt < NT; ++nt) acc[mi][nt] = (f32x4){0.f, 0.f, 0.f, 0.f};

#pragma unroll
  for (int kc = 0; kc < 4; ++kc) {
    int coff = (((kc * 4 + kq) ^ ln15) << 3);
    bf16x8 a0 = *(const bf16x8*)&As[((2 * wv + 0) * 16 + ln15) * 128 + coff];
    bf16x8 a1 = *(const bf16x8*)&As[((2 * wv + 1) * 16 + ln15) * 128 + coff];
#pragma unroll
    for (int nt = 0; nt < NT; ++nt) {
      bf16x8 b = *(const bf16x8*)&Ws[(nt * 16 + ln15) * 128 + coff];
      acc[0][nt] = __builtin_amdgcn_mfma_f32_16x16x32_bf16(a0, b, acc[0][nt], 0, 0, 0);
      acc[1][nt] = __builtin_amdgcn_mfma_f32_16x16x32_bf16(a1, b, acc[1][nt], 0, 0, 0);
    }
  }

  const int wbf = flg[0];
#pragma unroll
  for (int nt = 0; nt < NT; ++nt) {
    int col = nt * 16 + ln15;
    float bv = bias ? ld_f(bias, wbf, col) : 0.f;
#pragma unroll
    for (int mi = 0; mi < 2; ++mi) {
      int rbase = (2 * wv + mi) * 16 + kq * 4;
#pragma unroll
      for (int r = 0; r < 4; ++r) {
        int gr = r0 + rbase + r;
        if (gr < M) {
          float o = acc[mi][nt][r] + bv;
          if (RELU) o = fmaxf(o, 0.f);
          C[(size_t)gr * FOUT + col] = f2bfbits(o);
        }
      }
    }
  }
}

extern "C" void kernel_launch(void* const* d_in, const int* in_sizes, int n_in, void* d_out,
                              int out_size, void* d_ws, size_t ws_size, hipStream_t stream) {
  const void* x  = d_in[0];
  const void* ei = d_in[1];
  const void* ew = d_in[2];
  const void* W1 = d_in[3];
  const void* b1 = d_in[4];
  const void* W2 = d_in[5];
  const void* b2 = d_in[6];

  const int N = in_sizes[0] / FIN;  // 50000
  const int E = in_sizes[1] / 2;    // 800000
  const int B = 256;
  const int NB = (N + B - 1) / B;

  // ws layout: flags[16]i | cnt[N]i | rowptr[N]i | bsums[256]i | fill[N]i | degdinv[N]f |
  //   csr_src[E]i | csr_w[E]f | Wt1[128*128]bf | Wt2[64*128]bf |
  //   agg1[N*128]bf | H1[N*128]bf | hw2[N*64]bf   (~39 MB; all offsets 16B-aligned)
  int* flags   = (int*)d_ws;
  int* cnt     = flags + 16;
  int* rowptr  = cnt + N;
  int* bsums   = rowptr + N;
  int* fill    = bsums + 256;
  float* dinv  = (float*)(fill + N);  // deg then dinv in-place
  int* csr_src = (int*)(dinv + N);
  float* csr_w = (float*)(csr_src + E);
  unsigned short* Wt1 = (unsigned short*)(csr_w + E);
  unsigned short* Wt2 = Wt1 + 128 * 128;
  unsigned short* agg1 = Wt2 + 64 * 128;
  unsigned short* H1   = agg1 + (size_t)N * FHID;
  unsigned short* hw2  = H1 + (size_t)N * FHID;

  probe_kernel<<<1, 64, 0, stream>>>((const unsigned short*)x, (const unsigned*)ei, flags);
  transpose_w<<<(128 * 128 + 128 * 64) / B, B, 0, stream>>>(W1, W2, flags, Wt1, Wt2);

  // CSR build (by dst), weighted degree fused into count pass
  init_nd<<<NB, B, 0, stream>>>(cnt, dinv, N);
  count_edges<<<(E + B - 1) / B, B, 0, stream>>>(ei, ew, flags, cnt, dinv, E);
  calc_dinv<<<NB, B, 0, stream>>>(dinv, N);
  scanA<<<NB, B, 0, stream>>>(cnt, rowptr, bsums, N);
  scanB<<<1, B, 0, stream>>>(bsums, NB);
  scanC<<<NB, B, 0, stream>>>(rowptr, bsums, fill, N);
  fill_edges<<<(E + B - 1) / B, B, 0, stream>>>(ei, ew, flags, dinv, fill, csr_src, csr_w, E);

  // layer 1: agg1 = gather(x) [bf16]; H1 = relu(agg1 @ W1 + b1) [bf16, MFMA]
  gather_l1<<<(N + 3) / 4, B, 0, stream>>>(x, flags, rowptr, cnt, csr_src, csr_w, dinv,
                                           (unsigned*)agg1, N);
  gemm_mfma<FHID, true><<<(N + 127) / 128, B, 0, stream>>>(agg1, Wt1, b1, flags, H1, N);

  // layer 2: hw2 = H1 @ W2 [bf16, MFMA]; out = gather(hw2) + b2
  gemm_mfma<FOUTC, false><<<(N + 127) / 128, B, 0, stream>>>(H1, Wt2, nullptr, flags, hw2, N);
  gather_l2<<<(N + 3) / 4, B, 0, stream>>>(hw2, flags, rowptr, cnt, csr_src, csr_w, dinv, b2,
                                           d_out, N);
}

// Round 5
// 273.539 us; speedup vs baseline: 8.0457x; 1.2176x over previous
//
#include <hip/hip_runtime.h>
#include <hip/hip_bf16.h>

// GraphReconstructionGCN: N=50000, E=800000, GCN 128 -> 128 -> 64.
// Round 5: ELL edge format (CAP=48) built in ONE atomic pass (replaces
// count+scan+fill CSR build; count_edges alone was 75us of atomic latency).
// Degree summed atomic-free from ELL rows; gemm1 runs in-place (H1 = agg1).
static constexpr int FIN   = 128;
static constexpr int FHID  = 128;
static constexpr int FOUTC = 64;
static constexpr int CAP   = 48;  // max in-degree slot count; P(Poisson(16) > 48) ~ 6e-11

typedef short bf16x8 __attribute__((ext_vector_type(8)));
typedef float f32x4 __attribute__((ext_vector_type(4)));

__device__ __forceinline__ float bfbits2f(unsigned short u) {
  union { unsigned i; float f; } c; c.i = ((unsigned)u) << 16; return c.f;
}
__device__ __forceinline__ void unpack_bf2(unsigned u, float& lo, float& hi) {
  union { unsigned i; float f; } a, b;
  a.i = u << 16;
  b.i = u & 0xffff0000u;
  lo = a.f; hi = b.f;
}
__device__ __forceinline__ unsigned short f2bfbits(float f) {
  union { float fv; unsigned i; } c; c.fv = f;
  unsigned i = c.i;
  unsigned r = i + 0x7FFFu + ((i >> 16) & 1u);  // RNE
  if ((i & 0x7F800000u) == 0x7F800000u) r = i;  // inf/nan passthrough
  return (unsigned short)(r >> 16);
}
__device__ __forceinline__ int ld_idx(const void* ei, int is64, long long off) {
  return is64 ? (int)((const long long*)ei)[off] : ((const int*)ei)[off];
}
__device__ __forceinline__ float ld_f(const void* p, int isbf, long long i) {
  return isbf ? bfbits2f(((const unsigned short*)p)[i]) : ((const float*)p)[i];
}

// Zero cnt[]; block 0/thread 0 also probes dtypes.
// flags[0]: 1 = float tensors bf16, 0 = f32. flags[1]: 1 = indices int64, 0 = int32.
__global__ void setup_kernel(const unsigned short* __restrict__ xb,
                             const unsigned* __restrict__ eiw, int* __restrict__ flags,
                             int* __restrict__ cnt, int n) {
  int i = blockIdx.x * 256 + threadIdx.x;
  if (i < n) cnt[i] = 0;
  if (i == 0) {
    int isbf = 1;
    for (int k = 0; k < 256; ++k) {
      unsigned e = (xb[2 * k] >> 7) & 0xFFu;
      if (e >= 0xC0u) { isbf = 0; break; }
    }
    int is64 = 1;
    for (int k = 0; k < 64; ++k)
      if (eiw[2 * k + 1] != 0u) { is64 = 0; break; }
    flags[0] = isbf;
    flags[1] = is64;
  }
}

// One pass: p = atomicAdd(cnt[d]); ell[d*CAP+p] = (src, raw w as f32)
__global__ void fill_ell(const void* __restrict__ ei, const void* __restrict__ ew,
                         const int* __restrict__ flg, int* __restrict__ cnt,
                         int* __restrict__ ell_src, float* __restrict__ ell_w, int E) {
  int e = blockIdx.x * 256 + threadIdx.x;
  if (e >= E) return;
  int is64 = flg[1];
  int s = ld_idx(ei, is64, e);
  int d = ld_idx(ei, is64, (long long)E + e);
  float w = ld_f(ew, flg[0], e);
  int p = atomicAdd(&cnt[d], 1);
  if (p < CAP) {
    ell_src[d * CAP + p] = s;
    ell_w[d * CAP + p] = w;
  }
}

// deg[i] = 1 + sum of row weights (contiguous, no atomics); dinv = rsqrt; clamp cnt.
__global__ void node_dinv(int* __restrict__ cnt, const float* __restrict__ ell_w,
                          float* __restrict__ dinv, int n) {
  int i = blockIdx.x * 256 + threadIdx.x;
  if (i >= n) return;
  int c = cnt[i];
  if (c > CAP) { c = CAP; cnt[i] = CAP; }
  const float* wr = ell_w + (size_t)i * CAP;
  float s = 1.0f;  // self-loop weight
  for (int j = 0; j < c; ++j) s += wr[j];
  dinv[i] = rsqrtf(s);
}

// ell_w[slot] *= dinv[src]  (dinv[dst] applied wave-uniformly in gathers)
__global__ void norm_fix(const int* __restrict__ cnt, const int* __restrict__ ell_src,
                         const float* __restrict__ dinv, float* __restrict__ ell_w, int n) {
  int gid = blockIdx.x * 256 + threadIdx.x;
  if (gid >= n * CAP) return;
  int node = gid / CAP;
  int slot = gid - node * CAP;
  if (slot < cnt[node]) ell_w[gid] *= dinv[ell_src[gid]];
}

// Wt1[n*128+k] = W1[k][n]; Wt2[n*128+k] = W2[k][n]  (bf16, dtype-converted)
__global__ void transpose_w(const void* __restrict__ W1, const void* __restrict__ W2,
                            const int* __restrict__ flg, unsigned short* __restrict__ Wt1,
                            unsigned short* __restrict__ Wt2) {
  int i = blockIdx.x * 256 + threadIdx.x;
  int f = flg[0];
  if (i < 128 * 128) {
    int k = i >> 7, n = i & 127;
    Wt1[n * 128 + k] = f2bfbits(ld_f(W1, f, i));
  } else {
    int j = i - 128 * 128;  // j < 128*64
    int k = j >> 6, n = j & 63;
    Wt2[n * 128 + k] = f2bfbits(ld_f(W2, f, j));
  }
}

// agg1[n,:] = dinv[n] * sum_e w_e*x[src_e] + dinv[n]^2 * x[n]; bf16 out.
// One wave per node, lane covers 2 features. Unroll 4 for MLP.
__launch_bounds__(256)
__global__ void gather_l1(const void* __restrict__ x, const int* __restrict__ flg,
                          const int* __restrict__ cnt, const int* __restrict__ ell_src,
                          const float* __restrict__ ell_w, const float* __restrict__ dinv,
                          unsigned* __restrict__ agg, int n) {
  int wid = (blockIdx.x * 256 + threadIdx.x) >> 6;
  int lane = threadIdx.x & 63;
  if (wid >= n) return;
  int st = wid * CAP, e = st + cnt[wid];
  float a0 = 0.f, a1 = 0.f;
  float di = dinv[wid];
  float l, h;
  if (flg[0]) {
    const unsigned* xb = (const unsigned*)x;  // 2 bf16/word, 64 words/row
    int j = st;
    for (; j + 4 <= e; j += 4) {
      int s0 = ell_src[j], s1 = ell_src[j + 1], s2 = ell_src[j + 2], s3 = ell_src[j + 3];
      float w0 = ell_w[j], w1 = ell_w[j + 1], w2 = ell_w[j + 2], w3 = ell_w[j + 3];
      unsigned u0 = xb[(size_t)s0 * 64 + lane];
      unsigned u1 = xb[(size_t)s1 * 64 + lane];
      unsigned u2 = xb[(size_t)s2 * 64 + lane];
      unsigned u3 = xb[(size_t)s3 * 64 + lane];
      unpack_bf2(u0, l, h); a0 = fmaf(w0, l, a0); a1 = fmaf(w0, h, a1);
      unpack_bf2(u1, l, h); a0 = fmaf(w1, l, a0); a1 = fmaf(w1, h, a1);
      unpack_bf2(u2, l, h); a0 = fmaf(w2, l, a0); a1 = fmaf(w2, h, a1);
      unpack_bf2(u3, l, h); a0 = fmaf(w3, l, a0); a1 = fmaf(w3, h, a1);
    }
    for (; j < e; ++j) {
      float w0 = ell_w[j];
      unpack_bf2(xb[(size_t)ell_src[j] * 64 + lane], l, h);
      a0 = fmaf(w0, l, a0); a1 = fmaf(w0, h, a1);
    }
    unpack_bf2(xb[(size_t)wid * 64 + lane], l, h);
  } else {
    const float2* xf = (const float2*)x;
    int j = st;
    for (; j + 4 <= e; j += 4) {
      int s0 = ell_src[j], s1 = ell_src[j + 1], s2 = ell_src[j + 2], s3 = ell_src[j + 3];
      float w0 = ell_w[j], w1 = ell_w[j + 1], w2 = ell_w[j + 2], w3 = ell_w[j + 3];
      float2 v0 = xf[(size_t)s0 * 64 + lane];
      float2 v1 = xf[(size_t)s1 * 64 + lane];
      float2 v2 = xf[(size_t)s2 * 64 + lane];
      float2 v3 = xf[(size_t)s3 * 64 + lane];
      a0 = fmaf(w0, v0.x, a0); a1 = fmaf(w0, v0.y, a1);
      a0 = fmaf(w1, v1.x, a0); a1 = fmaf(w1, v1.y, a1);
      a0 = fmaf(w2, v2.x, a0); a1 = fmaf(w2, v2.y, a1);
      a0 = fmaf(w3, v3.x, a0); a1 = fmaf(w3, v3.y, a1);
    }
    for (; j < e; ++j) {
      float w0 = ell_w[j];
      float2 v0 = xf[(size_t)ell_src[j] * 64 + lane];
      a0 = fmaf(w0, v0.x, a0); a1 = fmaf(w0, v0.y, a1);
    }
    float2 v = xf[(size_t)wid * 64 + lane];
    l = v.x; h = v.y;
  }
  a0 = di * a0 + di * di * l;
  a1 = di * a1 + di * di * h;
  agg[(size_t)wid * 64 + lane] =
      (unsigned)f2bfbits(a0) | ((unsigned)f2bfbits(a1) << 16);
}

// out[n,:] = dinv[n]*sum_e w_e*hw2[src_e] + dinv[n]^2*hw2[n] + b2; hw2 bf16 64-wide.
__launch_bounds__(256)
__global__ void gather_l2(const unsigned short* __restrict__ hw2, const int* __restrict__ flg,
                          const int* __restrict__ cnt, const int* __restrict__ ell_src,
                          const float* __restrict__ ell_w, const float* __restrict__ dinv,
                          const void* __restrict__ b2, void* __restrict__ out, int n) {
  int wid = (blockIdx.x * 256 + threadIdx.x) >> 6;
  int lane = threadIdx.x & 63;
  if (wid >= n) return;
  int st = wid * CAP, e = st + cnt[wid];
  float a = 0.f;
  int j = st;
  for (; j + 4 <= e; j += 4) {
    int s0 = ell_src[j], s1 = ell_src[j + 1], s2 = ell_src[j + 2], s3 = ell_src[j + 3];
    float w0 = ell_w[j], w1 = ell_w[j + 1], w2 = ell_w[j + 2], w3 = ell_w[j + 3];
    float v0 = bfbits2f(hw2[(size_t)s0 * 64 + lane]);
    float v1 = bfbits2f(hw2[(size_t)s1 * 64 + lane]);
    float v2 = bfbits2f(hw2[(size_t)s2 * 64 + lane]);
    float v3 = bfbits2f(hw2[(size_t)s3 * 64 + lane]);
    a = fmaf(w0, v0, a); a = fmaf(w1, v1, a);
    a = fmaf(w2, v2, a); a = fmaf(w3, v3, a);
  }
  for (; j < e; ++j)
    a = fmaf(ell_w[j], bfbits2f(hw2[(size_t)ell_src[j] * 64 + lane]), a);
  float di = dinv[wid];
  a = di * a + di * di * bfbits2f(hw2[(size_t)wid * 64 + lane]);
  int isbf = flg[0];
  a += ld_f(b2, isbf, lane);
  if (isbf) ((unsigned short*)out)[(size_t)wid * 64 + lane] = f2bfbits(a);
  else ((float*)out)[(size_t)wid * 64 + lane] = a;
}

// C[M,FOUT](bf16) = act(A[M,128](bf16) @ W + b), W given as Wt[n][k] bf16.
// Safe for C == A (tile staged to LDS before stores; blocks own disjoint rows).
// XOR-chunk-swizzled LDS. A-op layout m=lane&15,k=quad*8+j; C/D col=lane&15,row=quad*4+reg.
template <int FOUT, bool RELU>
__launch_bounds__(256)
__global__ void gemm_mfma(const unsigned short* __restrict__ A,
                          const unsigned short* __restrict__ Wt,
                          const void* __restrict__ bias, const int* __restrict__ flg,
                          unsigned short* __restrict__ C, int M) {
  constexpr int NT = FOUT / 16;
  __shared__ unsigned short As[128 * 128];
  __shared__ unsigned short Ws[FOUT * 128];
  const int tid = threadIdx.x;
  const int r0 = blockIdx.x * 128;

  for (int i = tid; i < 128 * 16; i += 256) {
    int r = i >> 4, c = i & 15;
    uint4 v = make_uint4(0u, 0u, 0u, 0u);
    if (r0 + r < M) v = *(const uint4*)(A + (size_t)(r0 + r) * 128 + c * 8);
    *(uint4*)&As[r * 128 + ((c ^ (r & 15)) << 3)] = v;
  }
  for (int i = tid; i < FOUT * 16; i += 256) {
    int r = i >> 4, c = i & 15;
    uint4 v = *(const uint4*)(Wt + (size_t)r * 128 + c * 8);
    *(uint4*)&Ws[r * 128 + ((c ^ (r & 15)) << 3)] = v;
  }
  __syncthreads();

  const int lane = tid & 63;
  const int wv = tid >> 6;
  const int ln15 = lane & 15;
  const int kq = lane >> 4;
  f32x4 acc[2][NT];
#pragma unroll
  for (int mi = 0; mi < 2; ++mi)
#pragma unroll
    for (int nt = 0; nt < NT; ++nt) acc[mi][nt] = (f32x4){0.f, 0.f, 0.f, 0.f};

#pragma unroll
  for (int kc = 0; kc < 4; ++kc) {
    int coff = (((kc * 4 + kq) ^ ln15) << 3);
    bf16x8 a0 = *(const bf16x8*)&As[((2 * wv + 0) * 16 + ln15) * 128 + coff];
    bf16x8 a1 = *(const bf16x8*)&As[((2 * wv + 1) * 16 + ln15) * 128 + coff];
#pragma unroll
    for (int nt = 0; nt < NT; ++nt) {
      bf16x8 b = *(const bf16x8*)&Ws[(nt * 16 + ln15) * 128 + coff];
      acc[0][nt] = __builtin_amdgcn_mfma_f32_16x16x32_bf16(a0, b, acc[0][nt], 0, 0, 0);
      acc[1][nt] = __builtin_amdgcn_mfma_f32_16x16x32_bf16(a1, b, acc[1][nt], 0, 0, 0);
    }
  }

  const int wbf = flg[0];
#pragma unroll
  for (int nt = 0; nt < NT; ++nt) {
    int col = nt * 16 + ln15;
    float bv = bias ? ld_f(bias, wbf, col) : 0.f;
#pragma unroll
    for (int mi = 0; mi < 2; ++mi) {
      int rbase = (2 * wv + mi) * 16 + kq * 4;
#pragma unroll
      for (int r = 0; r < 4; ++r) {
        int gr = r0 + rbase + r;
        if (gr < M) {
          float o = acc[mi][nt][r] + bv;
          if (RELU) o = fmaxf(o, 0.f);
          C[(size_t)gr * FOUT + col] = f2bfbits(o);
        }
      }
    }
  }
}

extern "C" void kernel_launch(void* const* d_in, const int* in_sizes, int n_in, void* d_out,
                              int out_size, void* d_ws, size_t ws_size, hipStream_t stream) {
  const void* x  = d_in[0];
  const void* ei = d_in[1];
  const void* ew = d_in[2];
  const void* W1 = d_in[3];
  const void* b1 = d_in[4];
  const void* W2 = d_in[5];
  const void* b2 = d_in[6];

  const int N = in_sizes[0] / FIN;  // 50000
  const int E = in_sizes[1] / 2;    // 800000
  const int B = 256;
  const int NB = (N + B - 1) / B;

  // ws layout: flags[16]i | cnt[N]i | dinv[N]f | Wt1[128*128]bf | Wt2[64*128]bf |
  //   ell_src[N*CAP]i | ell_w[N*CAP]f | agg1[N*128]bf (H1 in-place) | hw2[N*64]bf  (~39MB)
  int* flags   = (int*)d_ws;
  int* cnt     = flags + 16;
  float* dinv  = (float*)(cnt + N);
  unsigned short* Wt1 = (unsigned short*)(dinv + N);
  unsigned short* Wt2 = Wt1 + 128 * 128;
  int* ell_src = (int*)(Wt2 + 64 * 128);
  float* ell_w = (float*)(ell_src + (size_t)N * CAP);
  unsigned short* agg1 = (unsigned short*)(ell_w + (size_t)N * CAP);
  unsigned short* H1   = agg1;  // gemm1 in-place
  unsigned short* hw2  = agg1 + (size_t)N * FHID;

  setup_kernel<<<NB, B, 0, stream>>>((const unsigned short*)x, (const unsigned*)ei, flags, cnt, N);
  fill_ell<<<(E + B - 1) / B, B, 0, stream>>>(ei, ew, flags, cnt, ell_src, ell_w, E);
  node_dinv<<<NB, B, 0, stream>>>(cnt, ell_w, dinv, N);
  norm_fix<<<((N * CAP) + B - 1) / B, B, 0, stream>>>(cnt, ell_src, dinv, ell_w, N);
  transpose_w<<<(128 * 128 + 128 * 64) / B, B, 0, stream>>>(W1, W2, flags, Wt1, Wt2);

  gather_l1<<<(N + 3) / 4, B, 0, stream>>>(x, flags, cnt, ell_src, ell_w, dinv,
                                           (unsigned*)agg1, N);
  gemm_mfma<FHID, true><<<(N + 127) / 128, B, 0, stream>>>(agg1, Wt1, b1, flags, H1, N);
  gemm_mfma<FOUTC, false><<<(N + 127) / 128, B, 0, stream>>>(H1, Wt2, nullptr, flags, hw2, N);
  gather_l2<<<(N + 3) / 4, B, 0, stream>>>(hw2, flags, cnt, ell_src, ell_w, dinv, b2, d_out, N);
}

// Round 6
// 246.116 us; speedup vs baseline: 8.9422x; 1.1114x over previous
//
#include <hip/hip_runtime.h>
#include <hip/hip_bf16.h>

// GraphReconstructionGCN: N=50000, E=800000, GCN 128 -> 128 -> 64.
// Round 6: register-resident ELL rows in gathers (shfl-broadcast, unroll 8),
// fused GEMM1+GEMM2 (H1 lives in LDS only), wave-parallel node_dinv.
static constexpr int FIN   = 128;
static constexpr int FHID  = 128;
static constexpr int FOUTC = 64;
static constexpr int CAP   = 48;  // max in-degree slots; P(Poisson(16) > 48) ~ 6e-11

typedef short bf16x8 __attribute__((ext_vector_type(8)));
typedef float f32x4 __attribute__((ext_vector_type(4)));

__device__ __forceinline__ float bfbits2f(unsigned short u) {
  union { unsigned i; float f; } c; c.i = ((unsigned)u) << 16; return c.f;
}
__device__ __forceinline__ float wbits2f(unsigned u) {
  union { unsigned i; float f; } c; c.i = u; return c.f;
}
__device__ __forceinline__ unsigned f2wbits(float f) {
  union { float fv; unsigned i; } c; c.fv = f; return c.i;
}
__device__ __forceinline__ void unpack_bf2(unsigned u, float& lo, float& hi) {
  union { unsigned i; float f; } a, b;
  a.i = u << 16;
  b.i = u & 0xffff0000u;
  lo = a.f; hi = b.f;
}
__device__ __forceinline__ unsigned short f2bfbits(float f) {
  union { float fv; unsigned i; } c; c.fv = f;
  unsigned i = c.i;
  unsigned r = i + 0x7FFFu + ((i >> 16) & 1u);  // RNE
  if ((i & 0x7F800000u) == 0x7F800000u) r = i;  // inf/nan passthrough
  return (unsigned short)(r >> 16);
}
__device__ __forceinline__ int ld_idx(const void* ei, int is64, long long off) {
  return is64 ? (int)((const long long*)ei)[off] : ((const int*)ei)[off];
}
__device__ __forceinline__ float ld_f(const void* p, int isbf, long long i) {
  return isbf ? bfbits2f(((const unsigned short*)p)[i]) : ((const float*)p)[i];
}

// Zero cnt[]; thread 0 probes dtypes.
// flags[0]: 1 = float tensors bf16, 0 = f32. flags[1]: 1 = indices int64, 0 = int32.
__global__ void setup_kernel(const unsigned short* __restrict__ xb,
                             const unsigned* __restrict__ eiw, int* __restrict__ flags,
                             int* __restrict__ cnt, int n) {
  int i = blockIdx.x * 256 + threadIdx.x;
  if (i < n) cnt[i] = 0;
  if (i == 0) {
    int isbf = 1;
    for (int k = 0; k < 256; ++k) {
      unsigned e = (xb[2 * k] >> 7) & 0xFFu;
      if (e >= 0xC0u) { isbf = 0; break; }
    }
    int is64 = 1;
    for (int k = 0; k < 64; ++k)
      if (eiw[2 * k + 1] != 0u) { is64 = 0; break; }
    flags[0] = isbf;
    flags[1] = is64;
  }
}

// One pass: p = atomicAdd(cnt[d]); ell[d*CAP+p] = (src, w bits) as one 8B store.
__global__ void fill_ell(const void* __restrict__ ei, const void* __restrict__ ew,
                         const int* __restrict__ flg, int* __restrict__ cnt,
                         uint2* __restrict__ ell, int E) {
  int e = blockIdx.x * 256 + threadIdx.x;
  if (e >= E) return;
  int is64 = flg[1];
  int s = ld_idx(ei, is64, e);
  int d = ld_idx(ei, is64, (long long)E + e);
  float w = ld_f(ew, flg[0], e);
  int p = atomicAdd(&cnt[d], 1);
  if (p < CAP) ell[(size_t)d * CAP + p] = make_uint2((unsigned)s, f2wbits(w));
}

// Wave per node: lane-parallel weight sum -> dinv = rsqrt(1 + sum); clamp cnt.
__global__ void node_dinv(int* __restrict__ cnt, const uint2* __restrict__ ell,
                          float* __restrict__ dinv, int n) {
  int wid = (blockIdx.x * 256 + threadIdx.x) >> 6;
  int lane = threadIdx.x & 63;
  if (wid >= n) return;
  int c0 = cnt[wid];
  int c = c0 > CAP ? CAP : c0;
  uint2 rec = ell[(size_t)wid * CAP + (lane < CAP ? lane : CAP - 1)];
  float w = (lane < c) ? wbits2f(rec.y) : 0.f;
#pragma unroll
  for (int off = 1; off < 64; off <<= 1) w += __shfl_xor(w, off);
  if (lane == 0) {
    if (c0 > CAP) cnt[wid] = CAP;
    dinv[wid] = rsqrtf(1.f + w);
  }
}

// ell[slot].w *= dinv[src]   (dinv[dst] applied wave-uniformly in gathers)
__global__ void norm_fix(const int* __restrict__ cnt, uint2* __restrict__ ell,
                         const float* __restrict__ dinv, int n) {
  int gid = blockIdx.x * 256 + threadIdx.x;
  if (gid >= n * CAP) return;
  int node = gid / CAP;
  int slot = gid - node * CAP;
  if (slot < cnt[node]) {
    uint2 v = ell[gid];
    ((unsigned*)ell)[2 * gid + 1] = f2wbits(wbits2f(v.y) * dinv[v.x]);
  }
}

// Wt1[n*128+k] = W1[k][n]; Wt2[n*128+k] = W2[k][n]  (bf16, dtype-converted)
__global__ void transpose_w(const void* __restrict__ W1, const void* __restrict__ W2,
                            const int* __restrict__ flg, unsigned short* __restrict__ Wt1,
                            unsigned short* __restrict__ Wt2) {
  int i = blockIdx.x * 256 + threadIdx.x;
  int f = flg[0];
  if (i < 128 * 128) {
    int k = i >> 7, n = i & 127;
    Wt1[n * 128 + k] = f2bfbits(ld_f(W1, f, i));
  } else {
    int j = i - 128 * 128;  // j < 128*64
    int k = j >> 6, n = j & 63;
    Wt2[n * 128 + k] = f2bfbits(ld_f(W2, f, j));
  }
}

// agg1[n,:] = dinv[n]*sum_e w_e*x[src_e] + dinv[n]^2*x[n]; bf16 out. Wave per node.
// Edge list register-resident: lane j holds slot j; loop broadcasts via readlane.
__launch_bounds__(256)
__global__ void gather_l1(const void* __restrict__ x, const int* __restrict__ flg,
                          const int* __restrict__ cnt, const uint2* __restrict__ ell,
                          const float* __restrict__ dinv, unsigned* __restrict__ agg, int n) {
  int wid = (blockIdx.x * 256 + threadIdx.x) >> 6;
  int lane = threadIdx.x & 63;
  if (wid >= n) return;
  int c = cnt[wid];
  uint2 rec = ell[(size_t)wid * CAP + (lane < CAP ? lane : CAP - 1)];
  int rsrc = (int)rec.x;
  float rw = wbits2f(rec.y);
  float a0 = 0.f, a1 = 0.f;
  float di = dinv[wid];
  float l, h;
  int iters = (c + 7) >> 3;
  if (flg[0]) {
    const unsigned* xb = (const unsigned*)x;  // 2 bf16/word, 64 words/row
    for (int it = 0; it < iters; ++it) {
      int j = it * 8;
      int sa[8];
      float wa[8];
      unsigned ua[8];
#pragma unroll
      for (int t = 0; t < 8; ++t) {
        int idx = j + t;
        bool v = idx < c;
        int sl = v ? idx : 0;
        sa[t] = __shfl(rsrc, sl);
        float ww = __shfl(rw, sl);
        wa[t] = v ? ww : 0.f;
      }
#pragma unroll
      for (int t = 0; t < 8; ++t) ua[t] = xb[(size_t)sa[t] * 64 + lane];
#pragma unroll
      for (int t = 0; t < 8; ++t) {
        unpack_bf2(ua[t], l, h);
        a0 = fmaf(wa[t], l, a0);
        a1 = fmaf(wa[t], h, a1);
      }
    }
    unpack_bf2(xb[(size_t)wid * 64 + lane], l, h);
  } else {
    const float2* xf = (const float2*)x;
    for (int it = 0; it < iters; ++it) {
      int j = it * 8;
      int sa[8];
      float wa[8];
      float2 va[8];
#pragma unroll
      for (int t = 0; t < 8; ++t) {
        int idx = j + t;
        bool v = idx < c;
        int sl = v ? idx : 0;
        sa[t] = __shfl(rsrc, sl);
        float ww = __shfl(rw, sl);
        wa[t] = v ? ww : 0.f;
      }
#pragma unroll
      for (int t = 0; t < 8; ++t) va[t] = xf[(size_t)sa[t] * 64 + lane];
#pragma unroll
      for (int t = 0; t < 8; ++t) {
        a0 = fmaf(wa[t], va[t].x, a0);
        a1 = fmaf(wa[t], va[t].y, a1);
      }
    }
    float2 v = xf[(size_t)wid * 64 + lane];
    l = v.x; h = v.y;
  }
  a0 = di * a0 + di * di * l;
  a1 = di * a1 + di * di * h;
  agg[(size_t)wid * 64 + lane] = (unsigned)f2bfbits(a0) | ((unsigned)f2bfbits(a1) << 16);
}

// out[n,:] = dinv[n]*sum_e w_e*hw2[src_e] + dinv[n]^2*hw2[n] + b2; hw2 bf16 64-wide.
__launch_bounds__(256)
__global__ void gather_l2(const unsigned short* __restrict__ hw2, const int* __restrict__ flg,
                          const int* __restrict__ cnt, const uint2* __restrict__ ell,
                          const float* __restrict__ dinv, const void* __restrict__ b2,
                          void* __restrict__ out, int n) {
  int wid = (blockIdx.x * 256 + threadIdx.x) >> 6;
  int lane = threadIdx.x & 63;
  if (wid >= n) return;
  int c = cnt[wid];
  uint2 rec = ell[(size_t)wid * CAP + (lane < CAP ? lane : CAP - 1)];
  int rsrc = (int)rec.x;
  float rw = wbits2f(rec.y);
  float a = 0.f;
  int iters = (c + 7) >> 3;
  for (int it = 0; it < iters; ++it) {
    int j = it * 8;
    int sa[8];
    float wa[8];
    unsigned short va[8];
#pragma unroll
    for (int t = 0; t < 8; ++t) {
      int idx = j + t;
      bool v = idx < c;
      int sl = v ? idx : 0;
      sa[t] = __shfl(rsrc, sl);
      float ww = __shfl(rw, sl);
      wa[t] = v ? ww : 0.f;
    }
#pragma unroll
    for (int t = 0; t < 8; ++t) va[t] = hw2[(size_t)sa[t] * 64 + lane];
#pragma unroll
    for (int t = 0; t < 8; ++t) a = fmaf(wa[t], bfbits2f(va[t]), a);
  }
  float di = dinv[wid];
  a = di * a + di * di * bfbits2f(hw2[(size_t)wid * 64 + lane]);
  int isbf = flg[0];
  a += ld_f(b2, isbf, lane);
  if (isbf) ((unsigned short*)out)[(size_t)wid * 64 + lane] = f2bfbits(a);
  else ((float*)out)[(size_t)wid * 64 + lane] = a;
}

// Fused: H1 = relu(agg1 @ W1 + b1) [LDS only]; hw2 = H1 @ W2 [global bf16].
// 128 rows/block, 4 waves, 16x16x32 MFMA, XOR-chunk-swizzled LDS tiles.
// A-op layout m=lane&15,k=quad*8+j; C/D col=lane&15,row=quad*4+reg.
// Each wave owns rows [32wv,32wv+32): H1 written back into As rows it alone reads.
__launch_bounds__(256)
__global__ void gemm12(const unsigned short* __restrict__ agg1,
                       const unsigned short* __restrict__ Wt1,
                       const unsigned short* __restrict__ Wt2,
                       const void* __restrict__ b1, const int* __restrict__ flg,
                       unsigned short* __restrict__ hw2, int M) {
  __shared__ unsigned short As[128 * 128];   // 32 KB (A1 tile, then H1 tile)
  __shared__ unsigned short W1s[128 * 128];  // 32 KB
  __shared__ unsigned short W2s[64 * 128];   // 16 KB
  const int tid = threadIdx.x;
  const int r0 = blockIdx.x * 128;

  for (int i = tid; i < 128 * 16; i += 256) {
    int r = i >> 4, ch = i & 15;
    uint4 v = make_uint4(0u, 0u, 0u, 0u);
    if (r0 + r < M) v = *(const uint4*)(agg1 + (size_t)(r0 + r) * 128 + ch * 8);
    *(uint4*)&As[r * 128 + ((ch ^ (r & 15)) << 3)] = v;
  }
  for (int i = tid; i < 128 * 16; i += 256) {
    int r = i >> 4, ch = i & 15;
    uint4 v = *(const uint4*)(Wt1 + (size_t)r * 128 + ch * 8);
    *(uint4*)&W1s[r * 128 + ((ch ^ (r & 15)) << 3)] = v;
  }
  for (int i = tid; i < 64 * 16; i += 256) {
    int r = i >> 4, ch = i & 15;
    uint4 v = *(const uint4*)(Wt2 + (size_t)r * 128 + ch * 8);
    *(uint4*)&W2s[r * 128 + ((ch ^ (r & 15)) << 3)] = v;
  }
  __syncthreads();

  const int lane = tid & 63;
  const int wv = tid >> 6;
  const int ln15 = lane & 15;
  const int kq = lane >> 4;
  const int wbf = flg[0];

  // GEMM1: acc1[mi][nt] covers rows (2wv+mi)*16, cols nt*16
  f32x4 acc1[2][8];
#pragma unroll
  for (int mi = 0; mi < 2; ++mi)
#pragma unroll
    for (int nt = 0; nt < 8; ++nt) acc1[mi][nt] = (f32x4){0.f, 0.f, 0.f, 0.f};
#pragma unroll
  for (int kc = 0; kc < 4; ++kc) {
    int coff = (((kc * 4 + kq) ^ ln15) << 3);
    bf16x8 a0 = *(const bf16x8*)&As[((2 * wv + 0) * 16 + ln15) * 128 + coff];
    bf16x8 a1 = *(const bf16x8*)&As[((2 * wv + 1) * 16 + ln15) * 128 + coff];
#pragma unroll
    for (int nt = 0; nt < 8; ++nt) {
      bf16x8 b = *(const bf16x8*)&W1s[(nt * 16 + ln15) * 128 + coff];
      acc1[0][nt] = __builtin_amdgcn_mfma_f32_16x16x32_bf16(a0, b, acc1[0][nt], 0, 0, 0);
      acc1[1][nt] = __builtin_amdgcn_mfma_f32_16x16x32_bf16(a1, b, acc1[1][nt], 0, 0, 0);
    }
  }

  // Epilogue 1: H1 = relu(acc1 + b1) -> back into As (this wave's own rows)
#pragma unroll
  for (int nt = 0; nt < 8; ++nt) {
    int col = nt * 16 + ln15;
    float bv = ld_f(b1, wbf, col);
#pragma unroll
    for (int mi = 0; mi < 2; ++mi) {
#pragma unroll
      for (int r = 0; r < 4; ++r) {
        int row = 32 * wv + mi * 16 + kq * 4 + r;
        float o = fmaxf(acc1[mi][nt][r] + bv, 0.f);
        As[row * 128 + ((((col >> 3)) ^ (row & 15)) << 3) + (col & 7)] = f2bfbits(o);
      }
    }
  }
  __syncthreads();

  // GEMM2: acc2[mi][nt2] covers rows (2wv+mi)*16, cols nt2*16 (FOUT=64)
  f32x4 acc2[2][4];
#pragma unroll
  for (int mi = 0; mi < 2; ++mi)
#pragma unroll
    for (int nt = 0; nt < 4; ++nt) acc2[mi][nt] = (f32x4){0.f, 0.f, 0.f, 0.f};
#pragma unroll
  for (int kc = 0; kc < 4; ++kc) {
    int coff = (((kc * 4 + kq) ^ ln15) << 3);
    bf16x8 a0 = *(const bf16x8*)&As[((2 * wv + 0) * 16 + ln15) * 128 + coff];
    bf16x8 a1 = *(const bf16x8*)&As[((2 * wv + 1) * 16 + ln15) * 128 + coff];
#pragma unroll
    for (int nt = 0; nt < 4; ++nt) {
      bf16x8 b = *(const bf16x8*)&W2s[(nt * 16 + ln15) * 128 + coff];
      acc2[0][nt] = __builtin_amdgcn_mfma_f32_16x16x32_bf16(a0, b, acc2[0][nt], 0, 0, 0);
      acc2[1][nt] = __builtin_amdgcn_mfma_f32_16x16x32_bf16(a1, b, acc2[1][nt], 0, 0, 0);
    }
  }
#pragma unroll
  for (int nt = 0; nt < 4; ++nt) {
    int col = nt * 16 + ln15;
#pragma unroll
    for (int mi = 0; mi < 2; ++mi) {
#pragma unroll
      for (int r = 0; r < 4; ++r) {
        int gr = r0 + 32 * wv + mi * 16 + kq * 4 + r;
        if (gr < M) hw2[(size_t)gr * 64 + col] = f2bfbits(acc2[mi][nt][r]);
      }
    }
  }
}

extern "C" void kernel_launch(void* const* d_in, const int* in_sizes, int n_in, void* d_out,
                              int out_size, void* d_ws, size_t ws_size, hipStream_t stream) {
  const void* x  = d_in[0];
  const void* ei = d_in[1];
  const void* ew = d_in[2];
  const void* W1 = d_in[3];
  const void* b1 = d_in[4];
  const void* W2 = d_in[5];
  const void* b2 = d_in[6];

  const int N = in_sizes[0] / FIN;  // 50000
  const int E = in_sizes[1] / 2;    // 800000
  const int B = 256;
  const int NB = (N + B - 1) / B;

  // ws layout: flags[16]i | cnt[N]i | dinv[N]f | Wt1[128*128]bf | Wt2[64*128]bf |
  //   ell[N*CAP]uint2 | agg1[N*128]bf | hw2[N*64]bf   (~38.9 MB, 16B-aligned blocks)
  int* flags   = (int*)d_ws;
  int* cnt     = flags + 16;
  float* dinv  = (float*)(cnt + N);
  unsigned short* Wt1 = (unsigned short*)(dinv + N);
  unsigned short* Wt2 = Wt1 + 128 * 128;
  uint2* ell   = (uint2*)(Wt2 + 64 * 128);
  unsigned short* agg1 = (unsigned short*)(ell + (size_t)N * CAP);
  unsigned short* hw2  = agg1 + (size_t)N * FHID;

  setup_kernel<<<NB, B, 0, stream>>>((const unsigned short*)x, (const unsigned*)ei, flags, cnt, N);
  transpose_w<<<(128 * 128 + 128 * 64) / B, B, 0, stream>>>(W1, W2, flags, Wt1, Wt2);
  fill_ell<<<(E + B - 1) / B, B, 0, stream>>>(ei, ew, flags, cnt, ell, E);
  node_dinv<<<(N + 3) / 4, B, 0, stream>>>(cnt, ell, dinv, N);
  norm_fix<<<((N * CAP) + B - 1) / B, B, 0, stream>>>(cnt, ell, dinv, N);

  gather_l1<<<(N + 3) / 4, B, 0, stream>>>(x, flags, cnt, ell, dinv, (unsigned*)agg1, N);
  gemm12<<<(N + 127) / 128, B, 0, stream>>>(agg1, Wt1, Wt2, b1, flags, hw2, N);
  gather_l2<<<(N + 3) / 4, B, 0, stream>>>(hw2, flags, cnt, ell, dinv, b2, d_out, N);
}

// Round 7
// 242.763 us; speedup vs baseline: 9.0657x; 1.0138x over previous
//
#include <hip/hip_runtime.h>
#include <hip/hip_bf16.h>

// GraphReconstructionGCN: N=50000, E=800000, GCN 128 -> 128 -> 64.
// Round 7: 16B/lane gathers (1 VMEM instr = 4-8 edge rows, 16 rows in flight),
// norm fused into gathers (norm_fix deleted), padded atomic counters (1/line),
// 2-edge fill threads, transpose merged into setup (6 launches total).
static constexpr int FIN   = 128;
static constexpr int FHID  = 128;
static constexpr int FOUTC = 64;
static constexpr int CAP   = 48;  // max in-degree slots; P(Poisson(16) > 48) ~ 6e-11
static constexpr int CSTR  = 16;  // cnt stride (ints): one counter per 64B line

typedef short bf16x8 __attribute__((ext_vector_type(8)));
typedef float f32x4 __attribute__((ext_vector_type(4)));

__device__ __forceinline__ float bfbits2f(unsigned short u) {
  union { unsigned i; float f; } c; c.i = ((unsigned)u) << 16; return c.f;
}
__device__ __forceinline__ float wbits2f(unsigned u) {
  union { unsigned i; float f; } c; c.i = u; return c.f;
}
__device__ __forceinline__ unsigned f2wbits(float f) {
  union { float fv; unsigned i; } c; c.fv = f; return c.i;
}
__device__ __forceinline__ void unpack_bf2(unsigned u, float& lo, float& hi) {
  union { unsigned i; float f; } a, b;
  a.i = u << 16;
  b.i = u & 0xffff0000u;
  lo = a.f; hi = b.f;
}
__device__ __forceinline__ unsigned short f2bfbits(float f) {
  union { float fv; unsigned i; } c; c.fv = f;
  unsigned i = c.i;
  unsigned r = i + 0x7FFFu + ((i >> 16) & 1u);  // RNE
  if ((i & 0x7F800000u) == 0x7F800000u) r = i;  // inf/nan passthrough
  return (unsigned short)(r >> 16);
}
__device__ __forceinline__ int ld_idx(const void* ei, int is64, long long off) {
  return is64 ? (int)((const long long*)ei)[off] : ((const int*)ei)[off];
}
__device__ __forceinline__ float ld_f(const void* p, int isbf, long long i) {
  return isbf ? bfbits2f(((const unsigned short*)p)[i]) : ((const float*)p)[i];
}

// Zero padded cnt (one 64B line per node, coalesced); blocks 0..95 also probe
// dtypes (wave-parallel ballot) and transpose W1/W2 into bf16 Wt1/Wt2.
// flags[0]: 1 = floats bf16, 0 = f32. flags[1]: 1 = indices int64, 0 = int32.
__global__ void setup_kernel(const unsigned short* __restrict__ xb,
                             const unsigned* __restrict__ eiw,
                             const void* __restrict__ W1, const void* __restrict__ W2,
                             int* __restrict__ flags, int* __restrict__ cnt,
                             unsigned short* __restrict__ Wt1,
                             unsigned short* __restrict__ Wt2, int n) {
  const int tid = threadIdx.x;
  const int gid = blockIdx.x * 256 + tid;
  if (gid < n) {
    uint4 z = make_uint4(0u, 0u, 0u, 0u);
    uint4* p = (uint4*)(cnt + (size_t)gid * CSTR);
    p[0] = z; p[1] = z; p[2] = z; p[3] = z;
  }
  if (blockIdx.x < 96) {
    __shared__ int sflags[2];
    if (tid < 64) {  // wave 0: parallel probe, 64 samples each
      unsigned short xs = xb[2 * tid];
      unsigned long long mb = __ballot(((xs >> 7) & 0xFFu) >= 0xC0u);
      unsigned long long m2 = __ballot(eiw[2 * tid + 1] != 0u);
      if (tid == 0) {
        sflags[0] = (mb == 0ull);  // no huge exponents => bf16
        sflags[1] = (m2 == 0ull);  // all high words zero => int64
        if (blockIdx.x == 0) { flags[0] = sflags[0]; flags[1] = sflags[1]; }
      }
    }
    __syncthreads();
    int f = sflags[0];
    int i = blockIdx.x * 256 + tid;  // 0..24575 == 128*128 + 128*64
    if (i < 128 * 128) {
      int k = i >> 7, nn = i & 127;
      Wt1[nn * 128 + k] = f2bfbits(ld_f(W1, f, i));
    } else {
      int j = i - 128 * 128;
      int k = j >> 6, nn = j & 63;
      Wt2[nn * 128 + k] = f2bfbits(ld_f(W2, f, j));
    }
  }
}

// Two edges per thread (independent atomic chains); padded counters.
__global__ void fill_ell(const void* __restrict__ ei, const void* __restrict__ ew,
                         const int* __restrict__ flg, int* __restrict__ cnt,
                         uint2* __restrict__ ell, int E, int half) {
  int g = blockIdx.x * 256 + threadIdx.x;
  if (g >= half) return;
  int is64 = flg[1], isbf = flg[0];
  int s0 = ld_idx(ei, is64, g);
  int d0 = ld_idx(ei, is64, (long long)E + g);
  float w0 = ld_f(ew, isbf, g);
  int e1 = g + half;
  bool has1 = e1 < E;
  int s1 = 0, d1 = 0;
  float w1 = 0.f;
  if (has1) {
    s1 = ld_idx(ei, is64, e1);
    d1 = ld_idx(ei, is64, (long long)E + e1);
    w1 = ld_f(ew, isbf, e1);
  }
  int p0 = atomicAdd(&cnt[(size_t)d0 * CSTR], 1);
  int p1 = has1 ? atomicAdd(&cnt[(size_t)d1 * CSTR], 1) : CAP;
  if (p0 < CAP) ell[(size_t)d0 * CAP + p0] = make_uint2((unsigned)s0, f2wbits(w0));
  if (p1 < CAP) ell[(size_t)d1 * CAP + p1] = make_uint2((unsigned)s1, f2wbits(w1));
}

// Wave per node: lane-parallel raw-weight sum -> dinv = rsqrt(1 + sum); clamp cnt.
__global__ void node_dinv(int* __restrict__ cnt, const uint2* __restrict__ ell,
                          float* __restrict__ dinv, int n) {
  int wid = (blockIdx.x * 256 + threadIdx.x) >> 6;
  int lane = threadIdx.x & 63;
  if (wid >= n) return;
  int c0 = cnt[(size_t)wid * CSTR];
  int c = c0 > CAP ? CAP : c0;
  float w = 0.f;
  if (lane < c) w = wbits2f(ell[(size_t)wid * CAP + lane].y);
#pragma unroll
  for (int off = 1; off < 64; off <<= 1) w += __shfl_xor(w, off);
  if (lane == 0) {
    if (c0 > CAP) cnt[(size_t)wid * CSTR] = CAP;
    dinv[wid] = rsqrtf(1.f + w);
  }
}

// agg1[n,:] = dinv[n]*sum_e (w_e*dinv[src])*x[src_e] + dinv[n]^2*x[n]; bf16 out.
// Wave per node. Lane j holds slot j (src, w*dinv[src]); 16B/lane row loads:
// lanes split into 4 edge-groups x 16 feature-chunks; 1 VMEM instr = 4 edge rows.
__launch_bounds__(256)
__global__ void gather_l1(const void* __restrict__ x, const int* __restrict__ flg,
                          const int* __restrict__ cnt, const uint2* __restrict__ ell,
                          const float* __restrict__ dinv, uint4* __restrict__ agg, int n) {
  int wid = (blockIdx.x * 256 + threadIdx.x) >> 6;
  int lane = threadIdx.x & 63;
  if (wid >= n) return;
  int c = cnt[(size_t)wid * CSTR];
  float di = dinv[wid];
  uint2 rec = make_uint2(0u, 0u);
  if (lane < c) rec = ell[(size_t)wid * CAP + lane];
  int rsrc = (int)rec.x;
  float rw = (lane < c) ? wbits2f(rec.y) * dinv[rec.x] : 0.f;

  if (flg[0]) {
    const uint4* xv = (const uint4*)x;  // 16 uint4 (8 bf16 each) per row
    const int fgrp = lane & 15, egrp = lane >> 4;
    float acc[8];
#pragma unroll
    for (int k = 0; k < 8; ++k) acc[k] = 0.f;
    int iters = (c + 15) >> 4;
    for (int it = 0; it < iters; ++it) {
      int b = it * 16 + egrp;
      int i0 = b, i1 = b + 4, i2 = b + 8, i3 = b + 12;
      int s0 = __shfl(rsrc, i0), s1 = __shfl(rsrc, i1);
      int s2 = __shfl(rsrc, i2), s3 = __shfl(rsrc, i3);
      float w0 = __shfl(rw, i0), w1 = __shfl(rw, i1);
      float w2 = __shfl(rw, i2), w3 = __shfl(rw, i3);
      s0 = i0 < c ? s0 : wid; s1 = i1 < c ? s1 : wid;  // masked -> self row (hot)
      s2 = i2 < c ? s2 : wid; s3 = i3 < c ? s3 : wid;
      uint4 u0 = xv[(size_t)s0 * 16 + fgrp];
      uint4 u1 = xv[(size_t)s1 * 16 + fgrp];
      uint4 u2 = xv[(size_t)s2 * 16 + fgrp];
      uint4 u3 = xv[(size_t)s3 * 16 + fgrp];
      float l, h;
      unpack_bf2(u0.x, l, h); acc[0] = fmaf(w0, l, acc[0]); acc[1] = fmaf(w0, h, acc[1]);
      unpack_bf2(u0.y, l, h); acc[2] = fmaf(w0, l, acc[2]); acc[3] = fmaf(w0, h, acc[3]);
      unpack_bf2(u0.z, l, h); acc[4] = fmaf(w0, l, acc[4]); acc[5] = fmaf(w0, h, acc[5]);
      unpack_bf2(u0.w, l, h); acc[6] = fmaf(w0, l, acc[6]); acc[7] = fmaf(w0, h, acc[7]);
      unpack_bf2(u1.x, l, h); acc[0] = fmaf(w1, l, acc[0]); acc[1] = fmaf(w1, h, acc[1]);
      unpack_bf2(u1.y, l, h); acc[2] = fmaf(w1, l, acc[2]); acc[3] = fmaf(w1, h, acc[3]);
      unpack_bf2(u1.z, l, h); acc[4] = fmaf(w1, l, acc[4]); acc[5] = fmaf(w1, h, acc[5]);
      unpack_bf2(u1.w, l, h); acc[6] = fmaf(w1, l, acc[6]); acc[7] = fmaf(w1, h, acc[7]);
      unpack_bf2(u2.x, l, h); acc[0] = fmaf(w2, l, acc[0]); acc[1] = fmaf(w2, h, acc[1]);
      unpack_bf2(u2.y, l, h); acc[2] = fmaf(w2, l, acc[2]); acc[3] = fmaf(w2, h, acc[3]);
      unpack_bf2(u2.z, l, h); acc[4] = fmaf(w2, l, acc[4]); acc[5] = fmaf(w2, h, acc[5]);
      unpack_bf2(u2.w, l, h); acc[6] = fmaf(w2, l, acc[6]); acc[7] = fmaf(w2, h, acc[7]);
      unpack_bf2(u3.x, l, h); acc[0] = fmaf(w3, l, acc[0]); acc[1] = fmaf(w3, h, acc[1]);
      unpack_bf2(u3.y, l, h); acc[2] = fmaf(w3, l, acc[2]); acc[3] = fmaf(w3, h, acc[3]);
      unpack_bf2(u3.z, l, h); acc[4] = fmaf(w3, l, acc[4]); acc[5] = fmaf(w3, h, acc[5]);
      unpack_bf2(u3.w, l, h); acc[6] = fmaf(w3, l, acc[6]); acc[7] = fmaf(w3, h, acc[7]);
    }
#pragma unroll
    for (int k = 0; k < 8; ++k) {
      acc[k] += __shfl_xor(acc[k], 16);
      acc[k] += __shfl_xor(acc[k], 32);
    }
    if (lane < 16) {
      uint4 su = xv[(size_t)wid * 16 + fgrp];
      float s0, s1, s2, s3, s4, s5, s6, s7;
      unpack_bf2(su.x, s0, s1); unpack_bf2(su.y, s2, s3);
      unpack_bf2(su.z, s4, s5); unpack_bf2(su.w, s6, s7);
      float dd = di * di;
      float o0 = di * acc[0] + dd * s0, o1 = di * acc[1] + dd * s1;
      float o2 = di * acc[2] + dd * s2, o3 = di * acc[3] + dd * s3;
      float o4 = di * acc[4] + dd * s4, o5 = di * acc[5] + dd * s5;
      float o6 = di * acc[6] + dd * s6, o7 = di * acc[7] + dd * s7;
      uint4 pk;
      pk.x = (unsigned)f2bfbits(o0) | ((unsigned)f2bfbits(o1) << 16);
      pk.y = (unsigned)f2bfbits(o2) | ((unsigned)f2bfbits(o3) << 16);
      pk.z = (unsigned)f2bfbits(o4) | ((unsigned)f2bfbits(o5) << 16);
      pk.w = (unsigned)f2bfbits(o6) | ((unsigned)f2bfbits(o7) << 16);
      agg[(size_t)wid * 16 + fgrp] = pk;
    }
  } else {
    const float4* xf = (const float4*)x;  // 32 float4 per row
    const int fgrp = lane & 31, egrp = lane >> 5;
    float acc[4] = {0.f, 0.f, 0.f, 0.f};
    int it8 = (c + 7) >> 3;
    for (int it = 0; it < it8; ++it) {
      int b = it * 8 + egrp;
#pragma unroll
      for (int t = 0; t < 4; ++t) {
        int idx = b + t * 2;
        int s = __shfl(rsrc, idx);
        float w = __shfl(rw, idx);
        s = idx < c ? s : wid;
        float4 v = xf[(size_t)s * 32 + fgrp];
        acc[0] = fmaf(w, v.x, acc[0]); acc[1] = fmaf(w, v.y, acc[1]);
        acc[2] = fmaf(w, v.z, acc[2]); acc[3] = fmaf(w, v.w, acc[3]);
      }
    }
#pragma unroll
    for (int k = 0; k < 4; ++k) acc[k] += __shfl_xor(acc[k], 32);
    if (lane < 32) {
      float4 sv = xf[(size_t)wid * 32 + fgrp];
      float dd = di * di;
      float o0 = di * acc[0] + dd * sv.x, o1 = di * acc[1] + dd * sv.y;
      float o2 = di * acc[2] + dd * sv.z, o3 = di * acc[3] + dd * sv.w;
      uint2 pk;
      pk.x = (unsigned)f2bfbits(o0) | ((unsigned)f2bfbits(o1) << 16);
      pk.y = (unsigned)f2bfbits(o2) | ((unsigned)f2bfbits(o3) << 16);
      ((uint2*)agg)[(size_t)wid * 32 + fgrp] = pk;
    }
  }
}

// out[n,:] = dinv[n]*sum_e (w_e*dinv[src])*hw2[src_e] + dinv[n]^2*hw2[n] + b2.
// hw2 bf16 64-wide (128B rows): 8 edge-groups x 8 feature-chunks, 8 rows/VMEM.
__launch_bounds__(256)
__global__ void gather_l2(const unsigned short* __restrict__ hw2, const int* __restrict__ flg,
                          const int* __restrict__ cnt, const uint2* __restrict__ ell,
                          const float* __restrict__ dinv, const void* __restrict__ b2,
                          void* __restrict__ out, int n) {
  int wid = (blockIdx.x * 256 + threadIdx.x) >> 6;
  int lane = threadIdx.x & 63;
  if (wid >= n) return;
  int c = cnt[(size_t)wid * CSTR];
  float di = dinv[wid];
  uint2 rec = make_uint2(0u, 0u);
  if (lane < c) rec = ell[(size_t)wid * CAP + lane];
  int rsrc = (int)rec.x;
  float rw = (lane < c) ? wbits2f(rec.y) * dinv[rec.x] : 0.f;

  const uint4* hv = (const uint4*)hw2;  // 8 uint4 per row
  const int fgrp = lane & 7, egrp = lane >> 3;
  float acc[8];
#pragma unroll
  for (int k = 0; k < 8; ++k) acc[k] = 0.f;
  int iters = (c + 15) >> 4;
  for (int it = 0; it < iters; ++it) {
    int i0 = it * 16 + egrp, i1 = i0 + 8;
    int s0 = __shfl(rsrc, i0), s1 = __shfl(rsrc, i1);
    float w0 = __shfl(rw, i0), w1 = __shfl(rw, i1);
    s0 = i0 < c ? s0 : wid;
    s1 = i1 < c ? s1 : wid;
    uint4 u0 = hv[(size_t)s0 * 8 + fgrp];
    uint4 u1 = hv[(size_t)s1 * 8 + fgrp];
    float l, h;
    unpack_bf2(u0.x, l, h); acc[0] = fmaf(w0, l, acc[0]); acc[1] = fmaf(w0, h, acc[1]);
    unpack_bf2(u0.y, l, h); acc[2] = fmaf(w0, l, acc[2]); acc[3] = fmaf(w0, h, acc[3]);
    unpack_bf2(u0.z, l, h); acc[4] = fmaf(w0, l, acc[4]); acc[5] = fmaf(w0, h, acc[5]);
    unpack_bf2(u0.w, l, h); acc[6] = fmaf(w0, l, acc[6]); acc[7] = fmaf(w0, h, acc[7]);
    unpack_bf2(u1.x, l, h); acc[0] = fmaf(w1, l, acc[0]); acc[1] = fmaf(w1, h, acc[1]);
    unpack_bf2(u1.y, l, h); acc[2] = fmaf(w1, l, acc[2]); acc[3] = fmaf(w1, h, acc[3]);
    unpack_bf2(u1.z, l, h); acc[4] = fmaf(w1, l, acc[4]); acc[5] = fmaf(w1, h, acc[5]);
    unpack_bf2(u1.w, l, h); acc[6] = fmaf(w1, l, acc[6]); acc[7] = fmaf(w1, h, acc[7]);
  }
#pragma unroll
  for (int k = 0; k < 8; ++k) {
    acc[k] += __shfl_xor(acc[k], 8);
    acc[k] += __shfl_xor(acc[k], 16);
    acc[k] += __shfl_xor(acc[k], 32);
  }
  if (lane < 8) {
    int isbf = flg[0];
    uint4 su = hv[(size_t)wid * 8 + fgrp];
    float s0, s1, s2, s3, s4, s5, s6, s7;
    unpack_bf2(su.x, s0, s1); unpack_bf2(su.y, s2, s3);
    unpack_bf2(su.z, s4, s5); unpack_bf2(su.w, s6, s7);
    float dd = di * di;
    float o0 = di * acc[0] + dd * s0 + ld_f(b2, isbf, fgrp * 8 + 0);
    float o1 = di * acc[1] + dd * s1 + ld_f(b2, isbf, fgrp * 8 + 1);
    float o2 = di * acc[2] + dd * s2 + ld_f(b2, isbf, fgrp * 8 + 2);
    float o3 = di * acc[3] + dd * s3 + ld_f(b2, isbf, fgrp * 8 + 3);
    float o4 = di * acc[4] + dd * s4 + ld_f(b2, isbf, fgrp * 8 + 4);
    float o5 = di * acc[5] + dd * s5 + ld_f(b2, isbf, fgrp * 8 + 5);
    float o6 = di * acc[6] + dd * s6 + ld_f(b2, isbf, fgrp * 8 + 6);
    float o7 = di * acc[7] + dd * s7 + ld_f(b2, isbf, fgrp * 8 + 7);
    if (isbf) {
      uint4 pk;
      pk.x = (unsigned)f2bfbits(o0) | ((unsigned)f2bfbits(o1) << 16);
      pk.y = (unsigned)f2bfbits(o2) | ((unsigned)f2bfbits(o3) << 16);
      pk.z = (unsigned)f2bfbits(o4) | ((unsigned)f2bfbits(o5) << 16);
      pk.w = (unsigned)f2bfbits(o6) | ((unsigned)f2bfbits(o7) << 16);
      ((uint4*)out)[(size_t)wid * 8 + fgrp] = pk;
    } else {
      ((float4*)out)[(size_t)wid * 16 + fgrp * 2 + 0] = make_float4(o0, o1, o2, o3);
      ((float4*)out)[(size_t)wid * 16 + fgrp * 2 + 1] = make_float4(o4, o5, o6, o7);
    }
  }
}

// Fused: H1 = relu(agg1 @ W1 + b1) [LDS only]; hw2 = H1 @ W2 [global bf16].
// 128 rows/block, 4 waves, 16x16x32 MFMA, XOR-chunk-swizzled LDS tiles.
__launch_bounds__(256)
__global__ void gemm12(const unsigned short* __restrict__ agg1,
                       const unsigned short* __restrict__ Wt1,
                       const unsigned short* __restrict__ Wt2,
                       const void* __restrict__ b1, const int* __restrict__ flg,
                       unsigned short* __restrict__ hw2, int M) {
  __shared__ unsigned short As[128 * 128];
  __shared__ unsigned short W1s[128 * 128];
  __shared__ unsigned short W2s[64 * 128];
  const int tid = threadIdx.x;
  const int r0 = blockIdx.x * 128;

  for (int i = tid; i < 128 * 16; i += 256) {
    int r = i >> 4, ch = i & 15;
    uint4 v = make_uint4(0u, 0u, 0u, 0u);
    if (r0 + r < M) v = *(const uint4*)(agg1 + (size_t)(r0 + r) * 128 + ch * 8);
    *(uint4*)&As[r * 128 + ((ch ^ (r & 15)) << 3)] = v;
  }
  for (int i = tid; i < 128 * 16; i += 256) {
    int r = i >> 4, ch = i & 15;
    uint4 v = *(const uint4*)(Wt1 + (size_t)r * 128 + ch * 8);
    *(uint4*)&W1s[r * 128 + ((ch ^ (r & 15)) << 3)] = v;
  }
  for (int i = tid; i < 64 * 16; i += 256) {
    int r = i >> 4, ch = i & 15;
    uint4 v = *(const uint4*)(Wt2 + (size_t)r * 128 + ch * 8);
    *(uint4*)&W2s[r * 128 + ((ch ^ (r & 15)) << 3)] = v;
  }
  __syncthreads();

  const int lane = tid & 63;
  const int wv = tid >> 6;
  const int ln15 = lane & 15;
  const int kq = lane >> 4;
  const int wbf = flg[0];

  f32x4 acc1[2][8];
#pragma unroll
  for (int mi = 0; mi < 2; ++mi)
#pragma unroll
    for (int nt = 0; nt < 8; ++nt) acc1[mi][nt] = (f32x4){0.f, 0.f, 0.f, 0.f};
#pragma unroll
  for (int kc = 0; kc < 4; ++kc) {
    int coff = (((kc * 4 + kq) ^ ln15) << 3);
    bf16x8 a0 = *(const bf16x8*)&As[((2 * wv + 0) * 16 + ln15) * 128 + coff];
    bf16x8 a1 = *(const bf16x8*)&As[((2 * wv + 1) * 16 + ln15) * 128 + coff];
#pragma unroll
    for (int nt = 0; nt < 8; ++nt) {
      bf16x8 b = *(const bf16x8*)&W1s[(nt * 16 + ln15) * 128 + coff];
      acc1[0][nt] = __builtin_amdgcn_mfma_f32_16x16x32_bf16(a0, b, acc1[0][nt], 0, 0, 0);
      acc1[1][nt] = __builtin_amdgcn_mfma_f32_16x16x32_bf16(a1, b, acc1[1][nt], 0, 0, 0);
    }
  }

#pragma unroll
  for (int nt = 0; nt < 8; ++nt) {
    int col = nt * 16 + ln15;
    float bv = ld_f(b1, wbf, col);
#pragma unroll
    for (int mi = 0; mi < 2; ++mi) {
#pragma unroll
      for (int r = 0; r < 4; ++r) {
        int row = 32 * wv + mi * 16 + kq * 4 + r;
        float o = fmaxf(acc1[mi][nt][r] + bv, 0.f);
        As[row * 128 + ((((col >> 3)) ^ (row & 15)) << 3) + (col & 7)] = f2bfbits(o);
      }
    }
  }
  __syncthreads();

  f32x4 acc2[2][4];
#pragma unroll
  for (int mi = 0; mi < 2; ++mi)
#pragma unroll
    for (int nt = 0; nt < 4; ++nt) acc2[mi][nt] = (f32x4){0.f, 0.f, 0.f, 0.f};
#pragma unroll
  for (int kc = 0; kc < 4; ++kc) {
    int coff = (((kc * 4 + kq) ^ ln15) << 3);
    bf16x8 a0 = *(const bf16x8*)&As[((2 * wv + 0) * 16 + ln15) * 128 + coff];
    bf16x8 a1 = *(const bf16x8*)&As[((2 * wv + 1) * 16 + ln15) * 128 + coff];
#pragma unroll
    for (int nt = 0; nt < 4; ++nt) {
      bf16x8 b = *(const bf16x8*)&W2s[(nt * 16 + ln15) * 128 + coff];
      acc2[0][nt] = __builtin_amdgcn_mfma_f32_16x16x32_bf16(a0, b, acc2[0][nt], 0, 0, 0);
      acc2[1][nt] = __builtin_amdgcn_mfma_f32_16x16x32_bf16(a1, b, acc2[1][nt], 0, 0, 0);
    }
  }
#pragma unroll
  for (int nt = 0; nt < 4; ++nt) {
    int col = nt * 16 + ln15;
#pragma unroll
    for (int mi = 0; mi < 2; ++mi) {
#pragma unroll
      for (int r = 0; r < 4; ++r) {
        int gr = r0 + 32 * wv + mi * 16 + kq * 4 + r;
        if (gr < M) hw2[(size_t)gr * 64 + col] = f2bfbits(acc2[mi][nt][r]);
      }
    }
  }
}

extern "C" void kernel_launch(void* const* d_in, const int* in_sizes, int n_in, void* d_out,
                              int out_size, void* d_ws, size_t ws_size, hipStream_t stream) {
  const void* x  = d_in[0];
  const void* ei = d_in[1];
  const void* ew = d_in[2];
  const void* W1 = d_in[3];
  const void* b1 = d_in[4];
  const void* W2 = d_in[5];
  const void* b2 = d_in[6];

  const int N = in_sizes[0] / FIN;  // 50000
  const int E = in_sizes[1] / 2;    // 800000
  const int B = 256;
  const int NB = (N + B - 1) / B;

  // ws: flags[16]i | cnt[N*CSTR]i | dinv[N]f | Wt1[128*128]bf | Wt2[64*128]bf |
  //     ell[N*CAP]uint2 | agg1[N*128]bf | hw2[N*64]bf   (~42 MB, 16B-aligned)
  int* flags   = (int*)d_ws;
  int* cnt     = flags + 16;
  float* dinv  = (float*)(cnt + (size_t)N * CSTR);
  unsigned short* Wt1 = (unsigned short*)(dinv + N);
  unsigned short* Wt2 = Wt1 + 128 * 128;
  uint2* ell   = (uint2*)(Wt2 + 64 * 128);
  unsigned short* agg1 = (unsigned short*)(ell + (size_t)N * CAP);
  unsigned short* hw2  = agg1 + (size_t)N * FHID;

  const int half = (E + 1) / 2;
  setup_kernel<<<NB, B, 0, stream>>>((const unsigned short*)x, (const unsigned*)ei, W1, W2,
                                     flags, cnt, Wt1, Wt2, N);
  fill_ell<<<(half + B - 1) / B, B, 0, stream>>>(ei, ew, flags, cnt, ell, E, half);
  node_dinv<<<(N + 3) / 4, B, 0, stream>>>(cnt, ell, dinv, N);
  gather_l1<<<(N + 3) / 4, B, 0, stream>>>(x, flags, cnt, ell, dinv, (uint4*)agg1, N);
  gemm12<<<(N + 127) / 128, B, 0, stream>>>(agg1, Wt1, Wt2, b1, flags, hw2, N);
  gather_l2<<<(N + 3) / 4, B, 0, stream>>>(hw2, flags, cnt, ell, dinv, b2, d_out, N);
}

// Round 8
// 234.776 us; speedup vs baseline: 9.3741x; 1.0340x over previous
//
#include <hip/hip_runtime.h>
#include <hip/hip_bf16.h>

// GraphReconstructionGCN: N=50000, E=800000, GCN 128 -> 128 -> 64.
// Round 8: hash-slot ELL (64 slots/node) built with 64-bit atomicCAS linear
// probing -- spreads atomics over 8 lines/node (~2 ops/line vs 16) to kill the
// same-line serialization that bound fill_ell (60us, 13.3 G atomics/s).
// Gathers compact scattered valid slots in-wave via ballot + ds_permute.
static constexpr int FIN   = 128;
static constexpr int FHID  = 128;
static constexpr int FOUTC = 64;
static constexpr int CAP   = 64;  // hash slots per node; P(deg>64 | Poisson(16)) ~ 1e-15

typedef short bf16x8 __attribute__((ext_vector_type(8)));
typedef float f32x4 __attribute__((ext_vector_type(4)));

__device__ __forceinline__ float bfbits2f(unsigned short u) {
  union { unsigned i; float f; } c; c.i = ((unsigned)u) << 16; return c.f;
}
__device__ __forceinline__ float wbits2f(unsigned u) {
  union { unsigned i; float f; } c; c.i = u; return c.f;
}
__device__ __forceinline__ unsigned f2wbits(float f) {
  union { float fv; unsigned i; } c; c.fv = f; return c.i;
}
__device__ __forceinline__ void unpack_bf2(unsigned u, float& lo, float& hi) {
  union { unsigned i; float f; } a, b;
  a.i = u << 16;
  b.i = u & 0xffff0000u;
  lo = a.f; hi = b.f;
}
__device__ __forceinline__ unsigned short f2bfbits(float f) {
  union { float fv; unsigned i; } c; c.fv = f;
  unsigned i = c.i;
  unsigned r = i + 0x7FFFu + ((i >> 16) & 1u);  // RNE
  if ((i & 0x7F800000u) == 0x7F800000u) r = i;  // inf/nan passthrough
  return (unsigned short)(r >> 16);
}
__device__ __forceinline__ int ld_idx(const void* ei, int is64, long long off) {
  return is64 ? (int)((const long long*)ei)[off] : ((const int*)ei)[off];
}
__device__ __forceinline__ float ld_f(const void* p, int isbf, long long i) {
  return isbf ? bfbits2f(((const unsigned short*)p)[i]) : ((const float*)p)[i];
}

// Wave-compact the scattered valid ELL slots: lane's rec -> (rsrc, rw) where
// lanes [0,c) hold the c valid edges in rank order. Returns c.
__device__ __forceinline__ int compact_row(uint2 rec, int lane, const float* __restrict__ dinv,
                                           int& rsrc, float& rw) {
  unsigned long long m = __ballot(rec.y != 0u);
  int c = __popcll(m);
  int rank = __popcll(m & ((1ull << lane) - 1ull));
  int destl = (rec.y != 0u) ? rank : c + (lane - rank);
  rsrc = __builtin_amdgcn_ds_permute(destl << 2, (int)rec.x);
  int rwb = __builtin_amdgcn_ds_permute(destl << 2, (int)rec.y);
  rw = (lane < c) ? wbits2f((unsigned)rwb) * dinv[rsrc] : 0.f;
  return c;
}

// Probe dtypes + transpose W1/W2 into bf16 Wt1/Wt2 (96 blocks).
// flags[0]: 1 = floats bf16, 0 = f32. flags[1]: 1 = indices int64, 0 = int32.
__global__ void setup_kernel(const unsigned short* __restrict__ xb,
                             const unsigned* __restrict__ eiw,
                             const void* __restrict__ W1, const void* __restrict__ W2,
                             int* __restrict__ flags, unsigned short* __restrict__ Wt1,
                             unsigned short* __restrict__ Wt2) {
  const int tid = threadIdx.x;
  __shared__ int sflags[2];
  if (tid < 64) {  // wave 0: parallel probe, 64 samples
    unsigned short xs = xb[2 * tid];
    unsigned long long mb = __ballot(((xs >> 7) & 0xFFu) >= 0xC0u);
    unsigned long long m2 = __ballot(eiw[2 * tid + 1] != 0u);
    if (tid == 0) {
      sflags[0] = (mb == 0ull);  // no huge exponents => bf16
      sflags[1] = (m2 == 0ull);  // all high words zero => int64
      if (blockIdx.x == 0) { flags[0] = sflags[0]; flags[1] = sflags[1]; }
    }
  }
  __syncthreads();
  int f = sflags[0];
  int i = blockIdx.x * 256 + tid;  // 0..24575 == 128*128 + 128*64
  if (i < 128 * 128) {
    int k = i >> 7, nn = i & 127;
    Wt1[nn * 128 + k] = f2bfbits(ld_f(W1, f, i));
  } else {
    int j = i - 128 * 128;
    int k = j >> 6, nn = j & 63;
    Wt2[nn * 128 + k] = f2bfbits(ld_f(W2, f, j));
  }
}

// Claim hash slots: slot value = (wbits<<32)|src, empty = 0. Two edges/thread,
// initial CAS of both issued independently; linear-probe retries (rare).
__global__ void fill_ell(const void* __restrict__ ei, const void* __restrict__ ew,
                         const int* __restrict__ flg, unsigned long long* __restrict__ ell,
                         int E, int half) {
  int g = blockIdx.x * 256 + threadIdx.x;
  if (g >= half) return;
  int is64 = flg[1], isbf = flg[0];
  int sA = ld_idx(ei, is64, g);
  int dA = ld_idx(ei, is64, (long long)E + g);
  unsigned wA = f2wbits(ld_f(ew, isbf, g));
  int eB = g + half;
  bool hasB = eB < E;
  int sB = 0, dB = 0;
  unsigned wB = 0u;
  if (hasB) {
    sB = ld_idx(ei, is64, eB);
    dB = ld_idx(ei, is64, (long long)E + eB);
    wB = f2wbits(ld_f(ew, isbf, eB));
  }
  unsigned long long vA = ((unsigned long long)wA << 32) | (unsigned)sA;
  unsigned long long vB = ((unsigned long long)wB << 32) | (unsigned)sB;
  unsigned long long* rowA = ell + (size_t)dA * CAP;
  unsigned long long* rowB = ell + (size_t)dB * CAP;
  int pA = g & (CAP - 1), pB = eB & (CAP - 1);
  bool doneA = (vA == 0ull);            // zero-weight edge at src 0: exact no-op
  bool doneB = !hasB || (vB == 0ull);
  unsigned long long oA = doneA ? 0ull : atomicCAS(&rowA[pA], 0ull, vA);
  unsigned long long oB = doneB ? 0ull : atomicCAS(&rowB[pB], 0ull, vB);
  for (int t = 1; t < CAP && !doneA && oA != 0ull; ++t) {
    pA = (pA + 1) & (CAP - 1);
    oA = atomicCAS(&rowA[pA], 0ull, vA);
  }
  for (int t = 1; t < CAP && !doneB && oB != 0ull; ++t) {
    pB = (pB + 1) & (CAP - 1);
    oB = atomicCAS(&rowB[pB], 0ull, vB);
  }
}

// Wave per node: dinv = rsqrt(1 + sum of slot weights) (empty slots read 0.0).
__global__ void node_dinv(const uint2* __restrict__ ell, float* __restrict__ dinv, int n) {
  int wid = (blockIdx.x * 256 + threadIdx.x) >> 6;
  int lane = threadIdx.x & 63;
  if (wid >= n) return;
  float w = wbits2f(ell[(size_t)wid * CAP + lane].y);
#pragma unroll
  for (int off = 1; off < 64; off <<= 1) w += __shfl_xor(w, off);
  if (lane == 0) dinv[wid] = rsqrtf(1.f + w);
}

// agg1[n,:] = dinv[n]*sum_e (w_e*dinv[src])*x[src_e] + dinv[n]^2*x[n]; bf16 out.
// Wave per node; hash-row compacted in-wave; 16B/lane row loads (4 rows/VMEM).
__launch_bounds__(256)
__global__ void gather_l1(const void* __restrict__ x, const int* __restrict__ flg,
                          const uint2* __restrict__ ell, const float* __restrict__ dinv,
                          uint4* __restrict__ agg, int n) {
  int wid = (blockIdx.x * 256 + threadIdx.x) >> 6;
  int lane = threadIdx.x & 63;
  if (wid >= n) return;
  uint2 rec = ell[(size_t)wid * CAP + lane];
  int rsrc;
  float rw;
  int c = compact_row(rec, lane, dinv, rsrc, rw);
  float di = dinv[wid];

  if (flg[0]) {
    const uint4* xv = (const uint4*)x;  // 16 uint4 (8 bf16 each) per row
    const int fgrp = lane & 15, egrp = lane >> 4;
    float acc[8];
#pragma unroll
    for (int k = 0; k < 8; ++k) acc[k] = 0.f;
    int iters = (c + 15) >> 4;
    for (int it = 0; it < iters; ++it) {
      int b = it * 16 + egrp;
      int i0 = b, i1 = b + 4, i2 = b + 8, i3 = b + 12;
      int s0 = __shfl(rsrc, i0), s1 = __shfl(rsrc, i1);
      int s2 = __shfl(rsrc, i2), s3 = __shfl(rsrc, i3);
      float w0 = __shfl(rw, i0), w1 = __shfl(rw, i1);
      float w2 = __shfl(rw, i2), w3 = __shfl(rw, i3);
      s0 = i0 < c ? s0 : wid; s1 = i1 < c ? s1 : wid;  // masked -> self row (hot)
      s2 = i2 < c ? s2 : wid; s3 = i3 < c ? s3 : wid;
      uint4 u0 = xv[(size_t)s0 * 16 + fgrp];
      uint4 u1 = xv[(size_t)s1 * 16 + fgrp];
      uint4 u2 = xv[(size_t)s2 * 16 + fgrp];
      uint4 u3 = xv[(size_t)s3 * 16 + fgrp];
      float l, h;
      unpack_bf2(u0.x, l, h); acc[0] = fmaf(w0, l, acc[0]); acc[1] = fmaf(w0, h, acc[1]);
      unpack_bf2(u0.y, l, h); acc[2] = fmaf(w0, l, acc[2]); acc[3] = fmaf(w0, h, acc[3]);
      unpack_bf2(u0.z, l, h); acc[4] = fmaf(w0, l, acc[4]); acc[5] = fmaf(w0, h, acc[5]);
      unpack_bf2(u0.w, l, h); acc[6] = fmaf(w0, l, acc[6]); acc[7] = fmaf(w0, h, acc[7]);
      unpack_bf2(u1.x, l, h); acc[0] = fmaf(w1, l, acc[0]); acc[1] = fmaf(w1, h, acc[1]);
      unpack_bf2(u1.y, l, h); acc[2] = fmaf(w1, l, acc[2]); acc[3] = fmaf(w1, h, acc[3]);
      unpack_bf2(u1.z, l, h); acc[4] = fmaf(w1, l, acc[4]); acc[5] = fmaf(w1, h, acc[5]);
      unpack_bf2(u1.w, l, h); acc[6] = fmaf(w1, l, acc[6]); acc[7] = fmaf(w1, h, acc[7]);
      unpack_bf2(u2.x, l, h); acc[0] = fmaf(w2, l, acc[0]); acc[1] = fmaf(w2, h, acc[1]);
      unpack_bf2(u2.y, l, h); acc[2] = fmaf(w2, l, acc[2]); acc[3] = fmaf(w2, h, acc[3]);
      unpack_bf2(u2.z, l, h); acc[4] = fmaf(w2, l, acc[4]); acc[5] = fmaf(w2, h, acc[5]);
      unpack_bf2(u2.w, l, h); acc[6] = fmaf(w2, l, acc[6]); acc[7] = fmaf(w2, h, acc[7]);
      unpack_bf2(u3.x, l, h); acc[0] = fmaf(w3, l, acc[0]); acc[1] = fmaf(w3, h, acc[1]);
      unpack_bf2(u3.y, l, h); acc[2] = fmaf(w3, l, acc[2]); acc[3] = fmaf(w3, h, acc[3]);
      unpack_bf2(u3.z, l, h); acc[4] = fmaf(w3, l, acc[4]); acc[5] = fmaf(w3, h, acc[5]);
      unpack_bf2(u3.w, l, h); acc[6] = fmaf(w3, l, acc[6]); acc[7] = fmaf(w3, h, acc[7]);
    }
#pragma unroll
    for (int k = 0; k < 8; ++k) {
      acc[k] += __shfl_xor(acc[k], 16);
      acc[k] += __shfl_xor(acc[k], 32);
    }
    if (lane < 16) {
      uint4 su = xv[(size_t)wid * 16 + fgrp];
      float s0, s1, s2, s3, s4, s5, s6, s7;
      unpack_bf2(su.x, s0, s1); unpack_bf2(su.y, s2, s3);
      unpack_bf2(su.z, s4, s5); unpack_bf2(su.w, s6, s7);
      float dd = di * di;
      float o0 = di * acc[0] + dd * s0, o1 = di * acc[1] + dd * s1;
      float o2 = di * acc[2] + dd * s2, o3 = di * acc[3] + dd * s3;
      float o4 = di * acc[4] + dd * s4, o5 = di * acc[5] + dd * s5;
      float o6 = di * acc[6] + dd * s6, o7 = di * acc[7] + dd * s7;
      uint4 pk;
      pk.x = (unsigned)f2bfbits(o0) | ((unsigned)f2bfbits(o1) << 16);
      pk.y = (unsigned)f2bfbits(o2) | ((unsigned)f2bfbits(o3) << 16);
      pk.z = (unsigned)f2bfbits(o4) | ((unsigned)f2bfbits(o5) << 16);
      pk.w = (unsigned)f2bfbits(o6) | ((unsigned)f2bfbits(o7) << 16);
      agg[(size_t)wid * 16 + fgrp] = pk;
    }
  } else {
    const float4* xf = (const float4*)x;  // 32 float4 per row
    const int fgrp = lane & 31, egrp = lane >> 5;
    float acc[4] = {0.f, 0.f, 0.f, 0.f};
    int it8 = (c + 7) >> 3;
    for (int it = 0; it < it8; ++it) {
      int b = it * 8 + egrp;
#pragma unroll
      for (int t = 0; t < 4; ++t) {
        int idx = b + t * 2;
        int s = __shfl(rsrc, idx);
        float w = __shfl(rw, idx);
        s = idx < c ? s : wid;
        float4 v = xf[(size_t)s * 32 + fgrp];
        acc[0] = fmaf(w, v.x, acc[0]); acc[1] = fmaf(w, v.y, acc[1]);
        acc[2] = fmaf(w, v.z, acc[2]); acc[3] = fmaf(w, v.w, acc[3]);
      }
    }
#pragma unroll
    for (int k = 0; k < 4; ++k) acc[k] += __shfl_xor(acc[k], 32);
    if (lane < 32) {
      float4 sv = xf[(size_t)wid * 32 + fgrp];
      float dd = di * di;
      float o0 = di * acc[0] + dd * sv.x, o1 = di * acc[1] + dd * sv.y;
      float o2 = di * acc[2] + dd * sv.z, o3 = di * acc[3] + dd * sv.w;
      uint2 pk;
      pk.x = (unsigned)f2bfbits(o0) | ((unsigned)f2bfbits(o1) << 16);
      pk.y = (unsigned)f2bfbits(o2) | ((unsigned)f2bfbits(o3) << 16);
      ((uint2*)agg)[(size_t)wid * 32 + fgrp] = pk;
    }
  }
}

// out[n,:] = dinv[n]*sum_e (w_e*dinv[src])*hw2[src_e] + dinv[n]^2*hw2[n] + b2.
// hw2 bf16 64-wide (128B rows): 8 edge-groups x 8 feature-chunks, 8 rows/VMEM.
__launch_bounds__(256)
__global__ void gather_l2(const unsigned short* __restrict__ hw2, const int* __restrict__ flg,
                          const uint2* __restrict__ ell, const float* __restrict__ dinv,
                          const void* __restrict__ b2, void* __restrict__ out, int n) {
  int wid = (blockIdx.x * 256 + threadIdx.x) >> 6;
  int lane = threadIdx.x & 63;
  if (wid >= n) return;
  uint2 rec = ell[(size_t)wid * CAP + lane];
  int rsrc;
  float rw;
  int c = compact_row(rec, lane, dinv, rsrc, rw);
  float di = dinv[wid];

  const uint4* hv = (const uint4*)hw2;  // 8 uint4 per row
  const int fgrp = lane & 7, egrp = lane >> 3;
  float acc[8];
#pragma unroll
  for (int k = 0; k < 8; ++k) acc[k] = 0.f;
  int iters = (c + 15) >> 4;
  for (int it = 0; it < iters; ++it) {
    int i0 = it * 16 + egrp, i1 = i0 + 8;
    int s0 = __shfl(rsrc, i0), s1 = __shfl(rsrc, i1);
    float w0 = __shfl(rw, i0), w1 = __shfl(rw, i1);
    s0 = i0 < c ? s0 : wid;
    s1 = i1 < c ? s1 : wid;
    uint4 u0 = hv[(size_t)s0 * 8 + fgrp];
    uint4 u1 = hv[(size_t)s1 * 8 + fgrp];
    float l, h;
    unpack_bf2(u0.x, l, h); acc[0] = fmaf(w0, l, acc[0]); acc[1] = fmaf(w0, h, acc[1]);
    unpack_bf2(u0.y, l, h); acc[2] = fmaf(w0, l, acc[2]); acc[3] = fmaf(w0, h, acc[3]);
    unpack_bf2(u0.z, l, h); acc[4] = fmaf(w0, l, acc[4]); acc[5] = fmaf(w0, h, acc[5]);
    unpack_bf2(u0.w, l, h); acc[6] = fmaf(w0, l, acc[6]); acc[7] = fmaf(w0, h, acc[7]);
    unpack_bf2(u1.x, l, h); acc[0] = fmaf(w1, l, acc[0]); acc[1] = fmaf(w1, h, acc[1]);
    unpack_bf2(u1.y, l, h); acc[2] = fmaf(w1, l, acc[2]); acc[3] = fmaf(w1, h, acc[3]);
    unpack_bf2(u1.z, l, h); acc[4] = fmaf(w1, l, acc[4]); acc[5] = fmaf(w1, h, acc[5]);
    unpack_bf2(u1.w, l, h); acc[6] = fmaf(w1, l, acc[6]); acc[7] = fmaf(w1, h, acc[7]);
  }
#pragma unroll
  for (int k = 0; k < 8; ++k) {
    acc[k] += __shfl_xor(acc[k], 8);
    acc[k] += __shfl_xor(acc[k], 16);
    acc[k] += __shfl_xor(acc[k], 32);
  }
  if (lane < 8) {
    int isbf = flg[0];
    uint4 su = hv[(size_t)wid * 8 + fgrp];
    float s0, s1, s2, s3, s4, s5, s6, s7;
    unpack_bf2(su.x, s0, s1); unpack_bf2(su.y, s2, s3);
    unpack_bf2(su.z, s4, s5); unpack_bf2(su.w, s6, s7);
    float dd = di * di;
    float o0 = di * acc[0] + dd * s0 + ld_f(b2, isbf, fgrp * 8 + 0);
    float o1 = di * acc[1] + dd * s1 + ld_f(b2, isbf, fgrp * 8 + 1);
    float o2 = di * acc[2] + dd * s2 + ld_f(b2, isbf, fgrp * 8 + 2);
    float o3 = di * acc[3] + dd * s3 + ld_f(b2, isbf, fgrp * 8 + 3);
    float o4 = di * acc[4] + dd * s4 + ld_f(b2, isbf, fgrp * 8 + 4);
    float o5 = di * acc[5] + dd * s5 + ld_f(b2, isbf, fgrp * 8 + 5);
    float o6 = di * acc[6] + dd * s6 + ld_f(b2, isbf, fgrp * 8 + 6);
    float o7 = di * acc[7] + dd * s7 + ld_f(b2, isbf, fgrp * 8 + 7);
    if (isbf) {
      uint4 pk;
      pk.x = (unsigned)f2bfbits(o0) | ((unsigned)f2bfbits(o1) << 16);
      pk.y = (unsigned)f2bfbits(o2) | ((unsigned)f2bfbits(o3) << 16);
      pk.z = (unsigned)f2bfbits(o4) | ((unsigned)f2bfbits(o5) << 16);
      pk.w = (unsigned)f2bfbits(o6) | ((unsigned)f2bfbits(o7) << 16);
      ((uint4*)out)[(size_t)wid * 8 + fgrp] = pk;
    } else {
      ((float4*)out)[(size_t)wid * 16 + fgrp * 2 + 0] = make_float4(o0, o1, o2, o3);
      ((float4*)out)[(size_t)wid * 16 + fgrp * 2 + 1] = make_float4(o4, o5, o6, o7);
    }
  }
}

// Fused: H1 = relu(agg1 @ W1 + b1) [LDS only]; hw2 = H1 @ W2 [global bf16].
// 128 rows/block, 4 waves, 16x16x32 MFMA, XOR-chunk-swizzled LDS tiles.
__launch_bounds__(256)
__global__ void gemm12(const unsigned short* __restrict__ agg1,
                       const unsigned short* __restrict__ Wt1,
                       const unsigned short* __restrict__ Wt2,
                       const void* __restrict__ b1, const int* __restrict__ flg,
                       unsigned short* __restrict__ hw2, int M) {
  __shared__ unsigned short As[128 * 128];
  __shared__ unsigned short W1s[128 * 128];
  __shared__ unsigned short W2s[64 * 128];
  const int tid = threadIdx.x;
  const int r0 = blockIdx.x * 128;

  for (int i = tid; i < 128 * 16; i += 256) {
    int r = i >> 4, ch = i & 15;
    uint4 v = make_uint4(0u, 0u, 0u, 0u);
    if (r0 + r < M) v = *(const uint4*)(agg1 + (size_t)(r0 + r) * 128 + ch * 8);
    *(uint4*)&As[r * 128 + ((ch ^ (r & 15)) << 3)] = v;
  }
  for (int i = tid; i < 128 * 16; i += 256) {
    int r = i >> 4, ch = i & 15;
    uint4 v = *(const uint4*)(Wt1 + (size_t)r * 128 + ch * 8);
    *(uint4*)&W1s[r * 128 + ((ch ^ (r & 15)) << 3)] = v;
  }
  for (int i = tid; i < 64 * 16; i += 256) {
    int r = i >> 4, ch = i & 15;
    uint4 v = *(const uint4*)(Wt2 + (size_t)r * 128 + ch * 8);
    *(uint4*)&W2s[r * 128 + ((ch ^ (r & 15)) << 3)] = v;
  }
  __syncthreads();

  const int lane = tid & 63;
  const int wv = tid >> 6;
  const int ln15 = lane & 15;
  const int kq = lane >> 4;
  const int wbf = flg[0];

  f32x4 acc1[2][8];
#pragma unroll
  for (int mi = 0; mi < 2; ++mi)
#pragma unroll
    for (int nt = 0; nt < 8; ++nt) acc1[mi][nt] = (f32x4){0.f, 0.f, 0.f, 0.f};
#pragma unroll
  for (int kc = 0; kc < 4; ++kc) {
    int coff = (((kc * 4 + kq) ^ ln15) << 3);
    bf16x8 a0 = *(const bf16x8*)&As[((2 * wv + 0) * 16 + ln15) * 128 + coff];
    bf16x8 a1 = *(const bf16x8*)&As[((2 * wv + 1) * 16 + ln15) * 128 + coff];
#pragma unroll
    for (int nt = 0; nt < 8; ++nt) {
      bf16x8 b = *(const bf16x8*)&W1s[(nt * 16 + ln15) * 128 + coff];
      acc1[0][nt] = __builtin_amdgcn_mfma_f32_16x16x32_bf16(a0, b, acc1[0][nt], 0, 0, 0);
      acc1[1][nt] = __builtin_amdgcn_mfma_f32_16x16x32_bf16(a1, b, acc1[1][nt], 0, 0, 0);
    }
  }

#pragma unroll
  for (int nt = 0; nt < 8; ++nt) {
    int col = nt * 16 + ln15;
    float bv = ld_f(b1, wbf, col);
#pragma unroll
    for (int mi = 0; mi < 2; ++mi) {
#pragma unroll
      for (int r = 0; r < 4; ++r) {
        int row = 32 * wv + mi * 16 + kq * 4 + r;
        float o = fmaxf(acc1[mi][nt][r] + bv, 0.f);
        As[row * 128 + ((((col >> 3)) ^ (row & 15)) << 3) + (col & 7)] = f2bfbits(o);
      }
    }
  }
  __syncthreads();

  f32x4 acc2[2][4];
#pragma unroll
  for (int mi = 0; mi < 2; ++mi)
#pragma unroll
    for (int nt = 0; nt < 4; ++nt) acc2[mi][nt] = (f32x4){0.f, 0.f, 0.f, 0.f};
#pragma unroll
  for (int kc = 0; kc < 4; ++kc) {
    int coff = (((kc * 4 + kq) ^ ln15) << 3);
    bf16x8 a0 = *(const bf16x8*)&As[((2 * wv + 0) * 16 + ln15) * 128 + coff];
    bf16x8 a1 = *(const bf16x8*)&As[((2 * wv + 1) * 16 + ln15) * 128 + coff];
#pragma unroll
    for (int nt = 0; nt < 4; ++nt) {
      bf16x8 b = *(const bf16x8*)&W2s[(nt * 16 + ln15) * 128 + coff];
      acc2[0][nt] = __builtin_amdgcn_mfma_f32_16x16x32_bf16(a0, b, acc2[0][nt], 0, 0, 0);
      acc2[1][nt] = __builtin_amdgcn_mfma_f32_16x16x32_bf16(a1, b, acc2[1][nt], 0, 0, 0);
    }
  }
#pragma unroll
  for (int nt = 0; nt < 4; ++nt) {
    int col = nt * 16 + ln15;
#pragma unroll
    for (int mi = 0; mi < 2; ++mi) {
#pragma unroll
      for (int r = 0; r < 4; ++r) {
        int gr = r0 + 32 * wv + mi * 16 + kq * 4 + r;
        if (gr < M) hw2[(size_t)gr * 64 + col] = f2bfbits(acc2[mi][nt][r]);
      }
    }
  }
}

extern "C" void kernel_launch(void* const* d_in, const int* in_sizes, int n_in, void* d_out,
                              int out_size, void* d_ws, size_t ws_size, hipStream_t stream) {
  const void* x  = d_in[0];
  const void* ei = d_in[1];
  const void* ew = d_in[2];
  const void* W1 = d_in[3];
  const void* b1 = d_in[4];
  const void* W2 = d_in[5];
  const void* b2 = d_in[6];

  const int N = in_sizes[0] / FIN;  // 50000
  const int E = in_sizes[1] / 2;    // 800000
  const int B = 256;

  // ws: flags[16]i | dinv[N]f | Wt1[128*128]bf | Wt2[64*128]bf |
  //     ell[N*CAP]u64 (25.6MB) | agg1[N*128]bf | hw2[N*64]bf   (~45.1 MB)
  int* flags   = (int*)d_ws;
  float* dinv  = (float*)(flags + 16);
  unsigned short* Wt1 = (unsigned short*)(dinv + N);
  unsigned short* Wt2 = Wt1 + 128 * 128;
  unsigned long long* ell = (unsigned long long*)(Wt2 + 64 * 128);
  unsigned short* agg1 = (unsigned short*)(ell + (size_t)N * CAP);
  unsigned short* hw2  = agg1 + (size_t)N * FHID;

  const int half = (E + 1) / 2;
  hipMemsetAsync(ell, 0, (size_t)N * CAP * sizeof(unsigned long long), stream);
  setup_kernel<<<96, B, 0, stream>>>((const unsigned short*)x, (const unsigned*)ei, W1, W2,
                                     flags, Wt1, Wt2);
  fill_ell<<<(half + B - 1) / B, B, 0, stream>>>(ei, ew, flags, ell, E, half);
  node_dinv<<<(N + 3) / 4, B, 0, stream>>>((const uint2*)ell, dinv, N);
  gather_l1<<<(N + 3) / 4, B, 0, stream>>>(x, flags, (const uint2*)ell, dinv, (uint4*)agg1, N);
  gemm12<<<(N + 127) / 128, B, 0, stream>>>(agg1, Wt1, Wt2, b1, flags, hw2, N);
  gather_l2<<<(N + 3) / 4, B, 0, stream>>>(hw2, flags, (const uint2*)ell, dinv, b2, d_out, N);
}